// Round 2
// baseline (574.167 us; speedup 1.0000x reference)
//
#include <hip/hip_runtime.h>
#include <hip/hip_fp16.h>

// GCN critic: 4 layers (128->16->16->16->1), symmetric gcn_norm with self-loops,
// global mean pool. N=100000 nodes, E=6400000 edges.
// R9 base + R11: k_agg16 restructured to __half2 feature pairs (8 feature lanes
// x 8 edge groups) -- halves VMEM instruction count and serial chain iterations.

#define BSHIFT 7
#define BSIZE 128            // nodes per dst bucket
#define NB_AL 800            // >= nbuck = ceil(100000/128) = 782
#define SCAN_N 1024          // scan width (pow2 >= nbuck)
#define CAPB 12288           // max padded records per bucket
#define NSRC_MASK 131071     // 17-bit src (src < 131072)
#define FBLK 512
#define FCHUNK 8192          // edges per hist/fill block
#define PADQ 8               // reservation quantum: 8 recs x 8B = one 64B line
#define SBLK 512
#define RPT (CAPB / SBLK)    // 24 records per thread in sortB

static __device__ __forceinline__ float relu_(float v) { return v > 0.f ? v : 0.f; }

static __device__ __forceinline__ float h2f_bits(unsigned short b) {
    __half_raw hr; hr.x = b;
    return __half2float(__half(hr));
}
static __device__ __forceinline__ unsigned short f2h_bits(float f) {
    __half h = __float2half(f);
    __half_raw hr = *(__half_raw*)&h;
    return hr.x;
}

// ---- zero bucket counters ----
__global__ __launch_bounds__(256) void k_zero(int* __restrict__ gbcnt, int nbuck) {
    int i = blockIdx.x * 256 + threadIdx.x;
    if (i < nbuck) gbcnt[i] = 0;
}

// ---- pass 1: per-block LDS histogram, accumulate PADDED per-block counts ----
__global__ __launch_bounds__(FBLK) void k_histA(const int* __restrict__ dst, int* __restrict__ gbcnt,
                                                int E, int nbuck) {
    __shared__ int hist[NB_AL];
    const int t = threadIdx.x;
    for (int i = t; i < nbuck; i += FBLK) hist[i] = 0;
    __syncthreads();
    const int c0 = blockIdx.x * FCHUNK;
    const int c1 = min(c0 + FCHUNK, E);
    for (int e = c0 + t; e < c1; e += FBLK)
        atomicAdd(&hist[dst[e] >> BSHIFT], 1);
    __syncthreads();
    for (int i = t; i < nbuck; i += FBLK) {
        int h = hist[i];
        if (h) atomicAdd(&gbcnt[i], (h + PADQ - 1) & ~(PADQ - 1));
    }
}

// ---- scan of padded counts: brow (exclusive) + bcur copy; one block ----
__global__ __launch_bounds__(1024) void k_scanA(const int* __restrict__ gbcnt, int* __restrict__ brow,
                                                int* __restrict__ bcur, int nbuck) {
    __shared__ int ps[1024];
    const int t = threadIdx.x;
    int i0 = t * 2, i1 = t * 2 + 1;
    int v0 = (i0 < nbuck) ? gbcnt[i0] : 0;
    int v1 = (i1 < nbuck) ? gbcnt[i1] : 0;
    int loc = v0 + v1;
    ps[t] = loc;
    __syncthreads();
    for (int o = 1; o < 1024; o <<= 1) {
        int x = 0;
        if (t >= o) x = ps[t - o];
        __syncthreads();
        ps[t] += x;
        __syncthreads();
    }
    int run = ps[t] - loc;
    if (i0 < nbuck) { brow[i0] = run; bcur[i0] = run; }
    if (i1 < nbuck) { brow[i1] = run + v0; bcur[i1] = run + v0; }
    if (t == 1023) brow[nbuck] = ps[1023];   // padded total
}

// ---- pass 2: LDS-staged fill. rec64 = fp16w<<32 | dstloc<<17 | src.
// Bucket-sorted staging in LDS, then flat coalesced flush of padded runs
// (full 64B lines, block-exclusive). Holes: w=0 records. ----
__global__ __launch_bounds__(FBLK) void k_fill(const int* __restrict__ src, const int* __restrict__ dst,
                                               const float* __restrict__ w, int* __restrict__ bcur,
                                               unsigned long long* __restrict__ ep, int E, int nbuck) {
    __shared__ unsigned long long stg[FCHUNK];   // 64 KB
    __shared__ int sc[SCAN_N];                   // packed (hp<<16)|cnt exclusive scan
    __shared__ int hist[NB_AL];
    __shared__ int cur[NB_AL];
    __shared__ int gbase[NB_AL];
    __shared__ int s_ptot;
    const int t = threadIdx.x;
    for (int i = t; i < nbuck; i += FBLK) hist[i] = 0;
    __syncthreads();
    const int c0 = blockIdx.x * FCHUNK;
    const int c1 = min(c0 + FCHUNK, E);
    for (int e = c0 + t; e < c1; e += FBLK)
        atomicAdd(&hist[dst[e] >> BSHIFT], 1);
    __syncthreads();
    // load packed values
    for (int i = t; i < SCAN_N; i += FBLK) {
        int c = (i < nbuck) ? hist[i] : 0;
        int hp = (c + PADQ - 1) & ~(PADQ - 1);
        sc[i] = (hp << 16) | c;
    }
    // Blelloch exclusive scan over SCAN_N
    for (int d = 1; d < SCAN_N; d <<= 1) {
        __syncthreads();
        int idx = (t + 1) * (d << 1) - 1;
        if (idx < SCAN_N) sc[idx] += sc[idx - d];
    }
    __syncthreads();
    if (t == 0) { s_ptot = sc[SCAN_N - 1]; sc[SCAN_N - 1] = 0; }
    for (int d = SCAN_N >> 1; d >= 1; d >>= 1) {
        __syncthreads();
        int idx = (t + 1) * (d << 1) - 1;
        if (idx < SCAN_N) { int tmp = sc[idx - d]; sc[idx - d] = sc[idx]; sc[idx] += tmp; }
    }
    __syncthreads();
    // reserve padded global ranges (line-aligned, block-exclusive) + init LDS cursors
    for (int i = t; i < nbuck; i += FBLK) {
        int c = hist[i];
        int hp = (c + PADQ - 1) & ~(PADQ - 1);
        gbase[i] = hp ? atomicAdd(&bcur[i], hp) : 0;
        cur[i] = sc[i] & 0xFFFF;   // lstart
    }
    __syncthreads();
    // scatter records into bucket-sorted LDS staging
    for (int e = c0 + t; e < c1; e += FBLK) {
        int d_ = dst[e];
        int b = d_ >> BSHIFT;
        int pos = atomicAdd(&cur[b], 1);
        stg[pos] = ((unsigned long long)f2h_bits(w[e]) << 32)
                 | ((unsigned)(d_ & (BSIZE - 1)) << 17) | (unsigned)src[e];
    }
    __syncthreads();
    // flat coalesced flush over padded total; binary search slot -> bucket
    const int ptot = s_ptot >> 16;
    for (int i = t; i < ptot; i += FBLK) {
        int lo = 0, hi = nbuck - 1;
        while (lo < hi) {
            int mid = (lo + hi + 1) >> 1;
            if ((sc[mid] >> 16) <= i) lo = mid; else hi = mid - 1;
        }
        int b = lo;
        int o = i - (sc[b] >> 16);
        int cb = hist[b];
        unsigned long long rec;
        if (o < cb) rec = stg[(sc[b] & 0xFFFF) + o];
        else rec = ((unsigned)(o & (BSIZE - 1))) << 17;   // hole: w=0
        ep[gbase[b] + o] = rec;
    }
}

// ---- stage B: register-staged in-bucket sort by dstloc; drops w=0 recs (holes);
// emits 4B recs (src<<15|w15) in place (upper half of own 8B region);
// deg/dis + per-node rs/re (in 4B-rec index units). ----
__global__ __launch_bounds__(SBLK) void k_sortB(unsigned long long* __restrict__ ep,
                                                const int* __restrict__ brow, float* __restrict__ dis,
                                                int* __restrict__ rs, int* __restrict__ re, int n) {
    __shared__ unsigned stg[CAPB];     // 48 KB
    __shared__ int hist[BSIZE];
    __shared__ int excl[BSIZE + 1];
    __shared__ int cur[BSIZE];
    __shared__ float degl[BSIZE];
    const int b = blockIdx.x, t = threadIdx.x;
    if (t < BSIZE) { hist[t] = 0; degl[t] = 0.f; }
    __syncthreads();
    const int base = brow[b];
    const int cnt = min(brow[b + 1] - base, CAPB);
    unsigned long long r[RPT];
#pragma unroll
    for (int k = 0; k < RPT; ++k) {
        int e = t + k * SBLK;
        if (e < cnt) r[k] = ep[base + e];
    }
    // pass 1: histogram + weighted degree (skip w=0: holes & null edges)
#pragma unroll
    for (int k = 0; k < RPT; ++k) {
        int e = t + k * SBLK;
        if (e < cnt) {
            unsigned w16 = (unsigned)(r[k] >> 32);
            if (w16) {
                int dl = ((unsigned)r[k] >> 17) & (BSIZE - 1);
                atomicAdd(&hist[dl], 1);
                atomicAdd(&degl[dl], h2f_bits((unsigned short)w16));
            }
        }
    }
    __syncthreads();
    if (t == 0) {
        int run = 0;
        for (int k2 = 0; k2 < BSIZE; ++k2) { excl[k2] = run; run += hist[k2]; }
        excl[BSIZE] = run;
    }
    __syncthreads();
    if (t < BSIZE) {
        cur[t] = excl[t];
        int node = (b << BSHIFT) + t;
        if (node < n) {
            dis[node] = (float)(1.0 / sqrt((double)(degl[t] + 1.0f)));   // +1 self-loop
            rs[node] = 2 * base + excl[t];          // 4B-rec index units
            re[node] = 2 * base + excl[t] + hist[t];
        }
    }
    __syncthreads();
    // pass 2: compress + scatter into LDS at sorted position
#pragma unroll
    for (int k = 0; k < RPT; ++k) {
        int e = t + k * SBLK;
        if (e < cnt) {
            unsigned w16 = (unsigned)(r[k] >> 32);
            if (w16) {
                int dl = ((unsigned)r[k] >> 17) & (BSIZE - 1);
                int pos = atomicAdd(&cur[dl], 1);
                stg[pos] = (((unsigned)r[k] & NSRC_MASK) << 15) | (w16 & 0x7FFF);
            }
        }
    }
    __syncthreads();
    // write back coalesced into the upper-aliased 4B view of OWN region (race-free)
    unsigned* outp = (unsigned*)(ep + base);
    const int m = excl[BSIZE];
    for (int i = t; i < m; i += SBLK) outp[i] = stg[i];
}

// ---- dense: zs = fp16( dis * (act(xin) @ W) ) ; act = relu(x + bprev) if RELU ----
template<int FI, int FO, bool RELU>
__global__ __launch_bounds__(256) void k_dense(const float* __restrict__ xin, const float* __restrict__ W,
                                               const float* __restrict__ bprev, const float* __restrict__ dis,
                                               __half* __restrict__ zs, int n) {
    constexpr int NPB = 256 / FO;
    constexpr int XP = FI + 1;
    __shared__ float Wl[FI * FO];
    __shared__ float xs[NPB * XP];
    const int t = threadIdx.x;
    for (int i = t; i < FI * FO; i += 256) Wl[i] = W[i];
    const int node0 = blockIdx.x * NPB;
    for (int i = t; i < NPB * FI; i += 256) {
        int r = i / FI, c = i - r * FI;
        int node = node0 + r;
        float v = 0.f;
        if (node < n) {
            v = xin[node * FI + c];
            if constexpr (RELU) v = relu_(v + bprev[c]);
        }
        xs[r * XP + c] = v;
    }
    __syncthreads();
    const int r = t / FO, j = t - r * FO;
    const int node = node0 + r;
    if (node < n) {
        float s = 0.f;
#pragma unroll
        for (int k = 0; k < FI; ++k) s += xs[r * XP + k] * Wl[k * FO + j];
        zs[node * FO + j] = __float2half(s * dis[node]);
    }
}

// ---- aggregation FO=16 (R11): one wave per node, __half2 feature pairs.
// 8 feature lanes (j2: features 2*j2, 2*j2+1) x 8 edge groups (g), 4 chains/lane.
// acc[d] = dis[d] * ( zs[d] + sum_e w_e * zs[src_e] )   (rec = src<<15|w15) ----
__global__ __launch_bounds__(256) void k_agg16(const unsigned* __restrict__ epc, const int* __restrict__ rs,
                                               const int* __restrict__ re, const float* __restrict__ dis,
                                               const __half* __restrict__ zs, float* __restrict__ acc, int n) {
    const int wv = (blockIdx.x * 256 + threadIdx.x) >> 6;   // node
    if (wv >= n) return;
    const int lane = threadIdx.x & 63;
    const int j2 = lane & 7, g = lane >> 3;
    const __half2* __restrict__ zs2 = (const __half2*)zs;
    const int base = rs[wv], end = re[wv];
    float sx = 0.f, sy = 0.f;
    int e = base + g;
    for (; e + 24 < end; e += 32) {     // 4 independent rec->zs chains, 32 recs/wave-iter
        unsigned r0 = epc[e], r1 = epc[e + 8], r2 = epc[e + 16], r3 = epc[e + 24];
        __half2 z0 = zs2[(r0 >> 15) * 8 + j2];
        __half2 z1 = zs2[(r1 >> 15) * 8 + j2];
        __half2 z2 = zs2[(r2 >> 15) * 8 + j2];
        __half2 z3 = zs2[(r3 >> 15) * 8 + j2];
        float w0 = h2f_bits((unsigned short)(r0 & 0x7FFF));
        float w1 = h2f_bits((unsigned short)(r1 & 0x7FFF));
        float w2 = h2f_bits((unsigned short)(r2 & 0x7FFF));
        float w3 = h2f_bits((unsigned short)(r3 & 0x7FFF));
        float2 f0 = __half22float2(z0), f1 = __half22float2(z1);
        float2 f2 = __half22float2(z2), f3 = __half22float2(z3);
        sx += f0.x * w0 + f1.x * w1 + f2.x * w2 + f3.x * w3;
        sy += f0.y * w0 + f1.y * w1 + f2.y * w2 + f3.y * w3;
    }
    for (; e < end; e += 8) {
        unsigned r0 = epc[e];
        float w0 = h2f_bits((unsigned short)(r0 & 0x7FFF));
        float2 f0 = __half22float2(zs2[(r0 >> 15) * 8 + j2]);
        sx += f0.x * w0;
        sy += f0.y * w0;
    }
    sx += __shfl_xor(sx, 8, 64);  sy += __shfl_xor(sy, 8, 64);
    sx += __shfl_xor(sx, 16, 64); sy += __shfl_xor(sy, 16, 64);
    sx += __shfl_xor(sx, 32, 64); sy += __shfl_xor(sy, 32, 64);
    if (g == 0) {
        float2 zself = __half22float2(zs2[wv * 8 + j2]);
        float d = dis[wv];
        ((float2*)acc)[wv * 8 + j2] = make_float2(d * (zself.x + sx), d * (zself.y + sy));
    }
}

// ---- aggregation FO=1 + relu+bias, per-block partial sums ----
__global__ __launch_bounds__(256) void k_agg1(const unsigned* __restrict__ epc, const int* __restrict__ rs,
                                              const int* __restrict__ re, const float* __restrict__ dis,
                                              const __half* __restrict__ zs1, const float* __restrict__ b4,
                                              float* __restrict__ partial, int n) {
    const int t = threadIdx.x;
    const int wv = (blockIdx.x * 256 + t) >> 6;
    const int lane = t & 63;
    float v = 0.f;
    if (wv < n) {
        const int base = rs[wv], end = re[wv];
        float s = 0.f;
        for (int e = base + lane; e < end; e += 64) {
            unsigned r = epc[e];
            s += __half2float(zs1[r >> 15]) * h2f_bits((unsigned short)(r & 0x7FFF));
        }
#pragma unroll
        for (int o = 32; o > 0; o >>= 1) s += __shfl_xor(s, o, 64);
        if (lane == 0) v = relu_(dis[wv] * (__half2float(zs1[wv]) + s) + b4[0]);
    }
    __shared__ float wsum[4];
    if (lane == 0) wsum[t >> 6] = v;
    __syncthreads();
    if (t == 0) partial[blockIdx.x] = wsum[0] + wsum[1] + wsum[2] + wsum[3];
}

// ---- final: out[0] = sum(partial) / n ; one block ----
__global__ __launch_bounds__(1024) void k_final(const float* __restrict__ partial, float* __restrict__ out,
                                                int nb, int n) {
    const int t = threadIdx.x;
    float s = 0.f;
    for (int i = t; i < nb; i += 1024) s += partial[i];
#pragma unroll
    for (int o = 32; o > 0; o >>= 1) s += __shfl_xor(s, o, 64);
    __shared__ float wsum[16];
    if ((t & 63) == 0) wsum[t >> 6] = s;
    __syncthreads();
    if (t == 0) {
        float tot = 0.f;
#pragma unroll
        for (int k = 0; k < 16; ++k) tot += wsum[k];
        out[0] = tot / (float)n;
    }
}

static inline size_t align_up(size_t x) { return (x + 255) & ~(size_t)255; }

extern "C" void kernel_launch(void* const* d_in, const int* in_sizes, int n_in,
                              void* d_out, int out_size, void* d_ws, size_t ws_size,
                              hipStream_t stream) {
    const float* vf  = (const float*)d_in[0];   // [N,128]
    const int*   edg = (const int*)d_in[1];     // [2,E] int32
    const float* w   = (const float*)d_in[2];   // [E]
    const float* W1  = (const float*)d_in[3];
    const float* b1  = (const float*)d_in[4];
    const float* W2  = (const float*)d_in[5];
    const float* b2  = (const float*)d_in[6];
    const float* W3  = (const float*)d_in[7];
    const float* b3  = (const float*)d_in[8];
    const float* W4  = (const float*)d_in[9];
    const float* b4  = (const float*)d_in[10];
    float* out = (float*)d_out;

    const int n = in_sizes[0] / 128;   // 100000
    const int E = in_sizes[2];         // 6400000
    const int* src = edg;
    const int* dst = edg + E;
    const int nbuck = (n + BSIZE - 1) >> BSHIFT;   // 782
    const int gB = (E + FCHUNK - 1) / FCHUNK;      // 782
    const size_t EPAD = (size_t)E + (size_t)gB * nbuck * (PADQ - 1) + 1024;  // worst-case padded

    char* ws = (char*)d_ws;
    size_t off = 0;
    int*                gbcnt   = (int*)(ws + off);                off += align_up((size_t)nbuck * 4);
    int*                brow    = (int*)(ws + off);                off += align_up((size_t)(nbuck + 1) * 4);
    int*                bcur    = (int*)(ws + off);                off += align_up((size_t)nbuck * 4);
    int*                rs      = (int*)(ws + off);                off += align_up((size_t)n * 4);
    int*                re      = (int*)(ws + off);                off += align_up((size_t)n * 4);
    float*              dis     = (float*)(ws + off);              off += align_up((size_t)n * 4);
    float*              partial = (float*)(ws + off);              off += align_up((size_t)((n + 3) / 4 + 1) * 4);
    unsigned long long* ep      = (unsigned long long*)(ws + off); off += align_up(EPAD * 8);
    __half*             zsb     = (__half*)(ws + off);             off += align_up((size_t)n * 16 * 2);
    float*              acc     = (float*)(ws + off);              off += align_up((size_t)n * 16 * 4);
    __half*             zs1     = zsb;   // layer-4 dense output aliases zs (only n halves used)
    (void)ws_size;

    const int gD16 = (n + 15) / 16;                      // dense FO=16: 16 nodes/block
    const int gN = (n + 255) / 256;
    const int gW = (n + 3) / 4;                          // wave-per-node kernels
    const unsigned* epc = (const unsigned*)ep;           // 4B post-sort view

    k_zero<<<(nbuck + 255) / 256, 256, 0, stream>>>(gbcnt, nbuck);
    k_histA<<<gB, FBLK, 0, stream>>>(dst, gbcnt, E, nbuck);
    k_scanA<<<1, 1024, 0, stream>>>(gbcnt, brow, bcur, nbuck);
    k_fill<<<gB, FBLK, 0, stream>>>(src, dst, w, bcur, ep, E, nbuck);
    k_sortB<<<nbuck, SBLK, 0, stream>>>(ep, brow, dis, rs, re, n);

    // layer 1: 128 -> 16
    k_dense<128, 16, false><<<gD16, 256, 0, stream>>>(vf, W1, nullptr, dis, zsb, n);
    k_agg16<<<gW, 256, 0, stream>>>(epc, rs, re, dis, zsb, acc, n);
    // layer 2: 16 -> 16
    k_dense<16, 16, true><<<gD16, 256, 0, stream>>>(acc, W2, b1, dis, zsb, n);
    k_agg16<<<gW, 256, 0, stream>>>(epc, rs, re, dis, zsb, acc, n);
    // layer 3: 16 -> 16
    k_dense<16, 16, true><<<gD16, 256, 0, stream>>>(acc, W3, b2, dis, zsb, n);
    k_agg16<<<gW, 256, 0, stream>>>(epc, rs, re, dis, zsb, acc, n);
    // layer 4: 16 -> 1, then aggregation + relu+bias into per-block partials
    k_dense<16, 1, true><<<gN, 256, 0, stream>>>(acc, W4, b3, dis, zs1, n);
    k_agg1<<<gW, 256, 0, stream>>>(epc, rs, re, dis, zs1, b4, partial, n);
    k_final<<<1, 1024, 0, stream>>>(partial, out, gW, n);
}

// Round 3
// 539.944 us; speedup vs baseline: 1.0634x; 1.0634x over previous
//
#include <hip/hip_runtime.h>
#include <hip/hip_fp16.h>

// GCN critic: 4 layers (128->16->16->16->1), symmetric gcn_norm with self-loops,
// global mean pool. N=100000 nodes, E=6400000 edges.
// R12: fixed-capacity bucket layout (CAPB slots/bucket) kills k_histA/k_scanA;
// k_fill flush = 16-lane-group bucket-run copy (no per-slot binary search).
// R11: k_agg16 __half2 feature pairs. Zero per-edge global atomics.

#define BSHIFT 7
#define BSIZE 128            // nodes per dst bucket
#define NB_AL 800            // >= nbuck = ceil(100000/128) = 782
#define SCAN_N 1024          // scan width (pow2 >= nbuck)
#define CAPB 12288           // fixed slots per bucket (mean 8192+2.7K holes, ~7 sigma margin)
#define NSRC_MASK 131071     // 17-bit src (src < 131072)
#define FBLK 512
#define FCHUNK 8192          // edges per fill block
#define PADQ 8               // reservation quantum: 8 recs x 8B = one 64B line
#define SBLK 512
#define RPT (CAPB / SBLK)    // 24 records per thread in sortB

static __device__ __forceinline__ float relu_(float v) { return v > 0.f ? v : 0.f; }

static __device__ __forceinline__ float h2f_bits(unsigned short b) {
    __half_raw hr; hr.x = b;
    return __half2float(__half(hr));
}
static __device__ __forceinline__ unsigned short f2h_bits(float f) {
    __half h = __float2half(f);
    __half_raw hr = *(__half_raw*)&h;
    return hr.x;
}

// ---- init bucket cursors to fixed bases ----
__global__ __launch_bounds__(256) void k_zero(int* __restrict__ bcur, int nbuck) {
    int i = blockIdx.x * 256 + threadIdx.x;
    if (i < nbuck) bcur[i] = i * CAPB;
}

// ---- fill: per-block hist -> local scan (lstart) -> LDS bucket-sorted staging ->
// global padded-run reservation (atomicAdd bcur) -> 16-lane-group run flush.
// rec64 = fp16w<<32 | dstloc<<17 | src. Holes: w=0 records. ----
__global__ __launch_bounds__(FBLK) void k_fill(const int* __restrict__ src, const int* __restrict__ dst,
                                               const float* __restrict__ w, int* __restrict__ bcur,
                                               unsigned long long* __restrict__ ep, int E, int nbuck) {
    __shared__ unsigned long long stg[FCHUNK];   // 64 KB
    __shared__ int sc[SCAN_N];                   // cnt exclusive scan -> lstart
    __shared__ int hist[NB_AL];
    __shared__ int cur[NB_AL];
    __shared__ int gbase[NB_AL];
    const int t = threadIdx.x;
    for (int i = t; i < nbuck; i += FBLK) hist[i] = 0;
    __syncthreads();
    const int c0 = blockIdx.x * FCHUNK;
    const int c1 = min(c0 + FCHUNK, E);
    for (int e = c0 + t; e < c1; e += FBLK)
        atomicAdd(&hist[dst[e] >> BSHIFT], 1);
    __syncthreads();
    for (int i = t; i < SCAN_N; i += FBLK) sc[i] = (i < nbuck) ? hist[i] : 0;
    // Blelloch exclusive scan over SCAN_N
    for (int d = 1; d < SCAN_N; d <<= 1) {
        __syncthreads();
        int idx = (t + 1) * (d << 1) - 1;
        if (idx < SCAN_N) sc[idx] += sc[idx - d];
    }
    __syncthreads();
    if (t == 0) sc[SCAN_N - 1] = 0;
    for (int d = SCAN_N >> 1; d >= 1; d >>= 1) {
        __syncthreads();
        int idx = (t + 1) * (d << 1) - 1;
        if (idx < SCAN_N) { int tmp = sc[idx - d]; sc[idx - d] = sc[idx]; sc[idx] += tmp; }
    }
    __syncthreads();
    // reserve padded global runs (line-aligned, block-exclusive) + init LDS cursors
    for (int i = t; i < nbuck; i += FBLK) {
        int c = hist[i];
        int hp = (c + PADQ - 1) & ~(PADQ - 1);
        gbase[i] = hp ? atomicAdd(&bcur[i], hp) : 0;
        cur[i] = sc[i];   // lstart
    }
    __syncthreads();
    // scatter records into bucket-sorted LDS staging
    for (int e = c0 + t; e < c1; e += FBLK) {
        int d_ = dst[e];
        int b = d_ >> BSHIFT;
        int pos = atomicAdd(&cur[b], 1);
        stg[pos] = ((unsigned long long)f2h_bits(w[e]) << 32)
                 | ((unsigned)(d_ & (BSIZE - 1)) << 17) | (unsigned)src[e];
    }
    __syncthreads();
    // flush: 16-lane groups copy whole padded bucket runs (coalesced full lines)
    const int grp = t >> 4, lgl = t & 15;            // 32 groups of 16 lanes
    for (int b = grp; b < nbuck; b += FBLK / 16) {
        int cb = hist[b];
        if (!cb) continue;
        int hp = (cb + PADQ - 1) & ~(PADQ - 1);
        int ls = sc[b];
        int gb = gbase[b];
        int lim = (b + 1) * CAPB;                    // capacity guard
        for (int o = lgl; o < hp; o += 16) {
            unsigned long long rec = (o < cb) ? stg[ls + o]
                : (((unsigned long long)(unsigned)(o & (BSIZE - 1))) << 17);   // hole: w=0
            int gi = gb + o;
            if (gi < lim) ep[gi] = rec;
        }
    }
}

// ---- stage B: register-staged in-bucket sort by dstloc; drops w=0 recs (holes);
// emits 4B recs (src<<15|w15) in place (upper half of own 8B region);
// deg/dis + per-node rs/re (in 4B-rec index units). base = b*CAPB fixed. ----
__global__ __launch_bounds__(SBLK) void k_sortB(unsigned long long* __restrict__ ep,
                                                const int* __restrict__ bcur, float* __restrict__ dis,
                                                int* __restrict__ rs, int* __restrict__ re, int n) {
    __shared__ unsigned stg[CAPB];     // 48 KB
    __shared__ int hist[BSIZE];
    __shared__ int excl[BSIZE + 1];
    __shared__ int cur[BSIZE];
    __shared__ float degl[BSIZE];
    const int b = blockIdx.x, t = threadIdx.x;
    if (t < BSIZE) { hist[t] = 0; degl[t] = 0.f; }
    __syncthreads();
    const int base = b * CAPB;
    const int cnt = min(bcur[b] - base, CAPB);
    unsigned long long r[RPT];
#pragma unroll
    for (int k = 0; k < RPT; ++k) {
        int e = t + k * SBLK;
        if (e < cnt) r[k] = ep[base + e];
    }
    // pass 1: histogram + weighted degree (skip w=0: holes)
#pragma unroll
    for (int k = 0; k < RPT; ++k) {
        int e = t + k * SBLK;
        if (e < cnt) {
            unsigned w16 = (unsigned)(r[k] >> 32);
            if (w16) {
                int dl = ((unsigned)r[k] >> 17) & (BSIZE - 1);
                atomicAdd(&hist[dl], 1);
                atomicAdd(&degl[dl], h2f_bits((unsigned short)w16));
            }
        }
    }
    __syncthreads();
    if (t == 0) {
        int run = 0;
        for (int k2 = 0; k2 < BSIZE; ++k2) { excl[k2] = run; run += hist[k2]; }
        excl[BSIZE] = run;
    }
    __syncthreads();
    if (t < BSIZE) {
        cur[t] = excl[t];
        int node = (b << BSHIFT) + t;
        if (node < n) {
            dis[node] = (float)(1.0 / sqrt((double)(degl[t] + 1.0f)));   // +1 self-loop
            rs[node] = 2 * base + excl[t];          // 4B-rec index units
            re[node] = 2 * base + excl[t] + hist[t];
        }
    }
    __syncthreads();
    // pass 2: compress + scatter into LDS at sorted position
#pragma unroll
    for (int k = 0; k < RPT; ++k) {
        int e = t + k * SBLK;
        if (e < cnt) {
            unsigned w16 = (unsigned)(r[k] >> 32);
            if (w16) {
                int dl = ((unsigned)r[k] >> 17) & (BSIZE - 1);
                int pos = atomicAdd(&cur[dl], 1);
                stg[pos] = (((unsigned)r[k] & NSRC_MASK) << 15) | (w16 & 0x7FFF);
            }
        }
    }
    __syncthreads();
    // write back coalesced into the upper-aliased 4B view of OWN region (race-free)
    unsigned* outp = (unsigned*)(ep + base);
    const int m = excl[BSIZE];
    for (int i = t; i < m; i += SBLK) outp[i] = stg[i];
}

// ---- dense: zs = fp16( dis * (act(xin) @ W) ) ; act = relu(x + bprev) if RELU ----
template<int FI, int FO, bool RELU>
__global__ __launch_bounds__(256) void k_dense(const float* __restrict__ xin, const float* __restrict__ W,
                                               const float* __restrict__ bprev, const float* __restrict__ dis,
                                               __half* __restrict__ zs, int n) {
    constexpr int NPB = 256 / FO;
    constexpr int XP = FI + 1;
    __shared__ float Wl[FI * FO];
    __shared__ float xs[NPB * XP];
    const int t = threadIdx.x;
    for (int i = t; i < FI * FO; i += 256) Wl[i] = W[i];
    const int node0 = blockIdx.x * NPB;
    for (int i = t; i < NPB * FI; i += 256) {
        int r = i / FI, c = i - r * FI;
        int node = node0 + r;
        float v = 0.f;
        if (node < n) {
            v = xin[node * FI + c];
            if constexpr (RELU) v = relu_(v + bprev[c]);
        }
        xs[r * XP + c] = v;
    }
    __syncthreads();
    const int r = t / FO, j = t - r * FO;
    const int node = node0 + r;
    if (node < n) {
        float s = 0.f;
#pragma unroll
        for (int k = 0; k < FI; ++k) s += xs[r * XP + k] * Wl[k * FO + j];
        zs[node * FO + j] = __float2half(s * dis[node]);
    }
}

// ---- aggregation FO=16 (R11): one wave per node, __half2 feature pairs.
// 8 feature lanes (j2: features 2*j2, 2*j2+1) x 8 edge groups (g), 4 chains/lane.
// acc[d] = dis[d] * ( zs[d] + sum_e w_e * zs[src_e] )   (rec = src<<15|w15) ----
__global__ __launch_bounds__(256) void k_agg16(const unsigned* __restrict__ epc, const int* __restrict__ rs,
                                               const int* __restrict__ re, const float* __restrict__ dis,
                                               const __half* __restrict__ zs, float* __restrict__ acc, int n) {
    const int wv = (blockIdx.x * 256 + threadIdx.x) >> 6;   // node
    if (wv >= n) return;
    const int lane = threadIdx.x & 63;
    const int j2 = lane & 7, g = lane >> 3;
    const __half2* __restrict__ zs2 = (const __half2*)zs;
    const int base = rs[wv], end = re[wv];
    float sx = 0.f, sy = 0.f;
    int e = base + g;
    for (; e + 24 < end; e += 32) {     // 4 independent rec->zs chains, 32 recs/wave-iter
        unsigned r0 = epc[e], r1 = epc[e + 8], r2 = epc[e + 16], r3 = epc[e + 24];
        __half2 z0 = zs2[(r0 >> 15) * 8 + j2];
        __half2 z1 = zs2[(r1 >> 15) * 8 + j2];
        __half2 z2 = zs2[(r2 >> 15) * 8 + j2];
        __half2 z3 = zs2[(r3 >> 15) * 8 + j2];
        float w0 = h2f_bits((unsigned short)(r0 & 0x7FFF));
        float w1 = h2f_bits((unsigned short)(r1 & 0x7FFF));
        float w2 = h2f_bits((unsigned short)(r2 & 0x7FFF));
        float w3 = h2f_bits((unsigned short)(r3 & 0x7FFF));
        float2 f0 = __half22float2(z0), f1 = __half22float2(z1);
        float2 f2 = __half22float2(z2), f3 = __half22float2(z3);
        sx += f0.x * w0 + f1.x * w1 + f2.x * w2 + f3.x * w3;
        sy += f0.y * w0 + f1.y * w1 + f2.y * w2 + f3.y * w3;
    }
    for (; e < end; e += 8) {
        unsigned r0 = epc[e];
        float w0 = h2f_bits((unsigned short)(r0 & 0x7FFF));
        float2 f0 = __half22float2(zs2[(r0 >> 15) * 8 + j2]);
        sx += f0.x * w0;
        sy += f0.y * w0;
    }
    sx += __shfl_xor(sx, 8, 64);  sy += __shfl_xor(sy, 8, 64);
    sx += __shfl_xor(sx, 16, 64); sy += __shfl_xor(sy, 16, 64);
    sx += __shfl_xor(sx, 32, 64); sy += __shfl_xor(sy, 32, 64);
    if (g == 0) {
        float2 zself = __half22float2(zs2[wv * 8 + j2]);
        float d = dis[wv];
        ((float2*)acc)[wv * 8 + j2] = make_float2(d * (zself.x + sx), d * (zself.y + sy));
    }
}

// ---- aggregation FO=1 + relu+bias, per-block partial sums ----
__global__ __launch_bounds__(256) void k_agg1(const unsigned* __restrict__ epc, const int* __restrict__ rs,
                                              const int* __restrict__ re, const float* __restrict__ dis,
                                              const __half* __restrict__ zs1, const float* __restrict__ b4,
                                              float* __restrict__ partial, int n) {
    const int t = threadIdx.x;
    const int wv = (blockIdx.x * 256 + t) >> 6;
    const int lane = t & 63;
    float v = 0.f;
    if (wv < n) {
        const int base = rs[wv], end = re[wv];
        float s = 0.f;
        for (int e = base + lane; e < end; e += 64) {
            unsigned r = epc[e];
            s += __half2float(zs1[r >> 15]) * h2f_bits((unsigned short)(r & 0x7FFF));
        }
#pragma unroll
        for (int o = 32; o > 0; o >>= 1) s += __shfl_xor(s, o, 64);
        if (lane == 0) v = relu_(dis[wv] * (__half2float(zs1[wv]) + s) + b4[0]);
    }
    __shared__ float wsum[4];
    if (lane == 0) wsum[t >> 6] = v;
    __syncthreads();
    if (t == 0) partial[blockIdx.x] = wsum[0] + wsum[1] + wsum[2] + wsum[3];
}

// ---- final: out[0] = sum(partial) / n ; one block ----
__global__ __launch_bounds__(1024) void k_final(const float* __restrict__ partial, float* __restrict__ out,
                                                int nb, int n) {
    const int t = threadIdx.x;
    float s = 0.f;
    for (int i = t; i < nb; i += 1024) s += partial[i];
#pragma unroll
    for (int o = 32; o > 0; o >>= 1) s += __shfl_xor(s, o, 64);
    __shared__ float wsum[16];
    if ((t & 63) == 0) wsum[t >> 6] = s;
    __syncthreads();
    if (t == 0) {
        float tot = 0.f;
#pragma unroll
        for (int k = 0; k < 16; ++k) tot += wsum[k];
        out[0] = tot / (float)n;
    }
}

static inline size_t align_up(size_t x) { return (x + 255) & ~(size_t)255; }

extern "C" void kernel_launch(void* const* d_in, const int* in_sizes, int n_in,
                              void* d_out, int out_size, void* d_ws, size_t ws_size,
                              hipStream_t stream) {
    const float* vf  = (const float*)d_in[0];   // [N,128]
    const int*   edg = (const int*)d_in[1];     // [2,E] int32
    const float* w   = (const float*)d_in[2];   // [E]
    const float* W1  = (const float*)d_in[3];
    const float* b1  = (const float*)d_in[4];
    const float* W2  = (const float*)d_in[5];
    const float* b2  = (const float*)d_in[6];
    const float* W3  = (const float*)d_in[7];
    const float* b3  = (const float*)d_in[8];
    const float* W4  = (const float*)d_in[9];
    const float* b4  = (const float*)d_in[10];
    float* out = (float*)d_out;

    const int n = in_sizes[0] / 128;   // 100000
    const int E = in_sizes[2];         // 6400000
    const int* src = edg;
    const int* dst = edg + E;
    const int nbuck = (n + BSIZE - 1) >> BSHIFT;   // 782
    const int gB = (E + FCHUNK - 1) / FCHUNK;      // 782

    char* ws = (char*)d_ws;
    size_t off = 0;
    int*                bcur    = (int*)(ws + off);                off += align_up((size_t)nbuck * 4);
    int*                rs      = (int*)(ws + off);                off += align_up((size_t)n * 4);
    int*                re      = (int*)(ws + off);                off += align_up((size_t)n * 4);
    float*              dis     = (float*)(ws + off);              off += align_up((size_t)n * 4);
    float*              partial = (float*)(ws + off);              off += align_up((size_t)((n + 3) / 4 + 1) * 4);
    unsigned long long* ep      = (unsigned long long*)(ws + off); off += align_up((size_t)nbuck * CAPB * 8);
    __half*             zsb     = (__half*)(ws + off);             off += align_up((size_t)n * 16 * 2);
    float*              acc     = (float*)(ws + off);              off += align_up((size_t)n * 16 * 4);
    __half*             zs1     = zsb;   // layer-4 dense output aliases zs (only n halves used)
    (void)ws_size;

    const int gD16 = (n + 15) / 16;                      // dense FO=16: 16 nodes/block
    const int gN = (n + 255) / 256;
    const int gW = (n + 3) / 4;                          // wave-per-node kernels
    const unsigned* epc = (const unsigned*)ep;           // 4B post-sort view

    k_zero<<<(nbuck + 255) / 256, 256, 0, stream>>>(bcur, nbuck);
    k_fill<<<gB, FBLK, 0, stream>>>(src, dst, w, bcur, ep, E, nbuck);
    k_sortB<<<nbuck, SBLK, 0, stream>>>(ep, bcur, dis, rs, re, n);

    // layer 1: 128 -> 16
    k_dense<128, 16, false><<<gD16, 256, 0, stream>>>(vf, W1, nullptr, dis, zsb, n);
    k_agg16<<<gW, 256, 0, stream>>>(epc, rs, re, dis, zsb, acc, n);
    // layer 2: 16 -> 16
    k_dense<16, 16, true><<<gD16, 256, 0, stream>>>(acc, W2, b1, dis, zsb, n);
    k_agg16<<<gW, 256, 0, stream>>>(epc, rs, re, dis, zsb, acc, n);
    // layer 3: 16 -> 16
    k_dense<16, 16, true><<<gD16, 256, 0, stream>>>(acc, W3, b2, dis, zsb, n);
    k_agg16<<<gW, 256, 0, stream>>>(epc, rs, re, dis, zsb, acc, n);
    // layer 4: 16 -> 1, then aggregation + relu+bias into per-block partials
    k_dense<16, 1, true><<<gN, 256, 0, stream>>>(acc, W4, b3, dis, zs1, n);
    k_agg1<<<gW, 256, 0, stream>>>(epc, rs, re, dis, zs1, b4, partial, n);
    k_final<<<1, 1024, 0, stream>>>(partial, out, gW, n);
}

// Round 4
// 538.076 us; speedup vs baseline: 1.0671x; 1.0035x over previous
//
#include <hip/hip_runtime.h>
#include <hip/hip_fp16.h>

// GCN critic: 4 layers (128->16->16->16->1), symmetric gcn_norm with self-loops,
// global mean pool. N=100000 nodes, E=6400000 edges.
// R13: bcur cursors padded to one 64B line each (kills global-atomic line
// contention); scatter uses rank returned by pass-1 hist atomicAdd (no LDS cur
// atomics, no dst re-read). R12: fixed-capacity buckets, group-run flush.
// R11: k_agg16 __half2 feature pairs. Zero per-edge global atomics.

#define BSHIFT 7
#define BSIZE 128            // nodes per dst bucket
#define NB_AL 800            // >= nbuck = ceil(100000/128) = 782
#define SCAN_N 1024          // scan width (pow2 >= nbuck)
#define CAPB 12288           // fixed slots per bucket (~12 sigma margin)
#define BSTRIDE 16           // ints per bucket cursor (one 64B line)
#define NSRC_MASK 131071     // 17-bit src (src < 131072)
#define FBLK 512
#define FCHUNK 8192          // edges per fill block
#define FRPT (FCHUNK / FBLK) // 16 edges per thread in fill
#define PADQ 8               // reservation quantum: 8 recs x 8B = one 64B line
#define SBLK 512
#define RPT (CAPB / SBLK)    // 24 records per thread in sortB

static __device__ __forceinline__ float relu_(float v) { return v > 0.f ? v : 0.f; }

static __device__ __forceinline__ float h2f_bits(unsigned short b) {
    __half_raw hr; hr.x = b;
    return __half2float(__half(hr));
}
static __device__ __forceinline__ unsigned short f2h_bits(float f) {
    __half h = __float2half(f);
    __half_raw hr = *(__half_raw*)&h;
    return hr.x;
}

// ---- init bucket cursors to fixed bases (line-padded) ----
__global__ __launch_bounds__(256) void k_zero(int* __restrict__ bcur, int nbuck) {
    int i = blockIdx.x * 256 + threadIdx.x;
    if (i < nbuck) bcur[i * BSTRIDE] = i * CAPB;
}

// ---- fill: pass1 hist (atomicAdd return = in-bucket rank, kept in VGPRs) ->
// local scan (lstart) -> padded-run reservation (line-padded global atomics) ->
// rank-addressed LDS staging scatter -> 16-lane-group run flush.
// rec64 = fp16w<<32 | dstloc<<17 | src. Holes: w=0 records. ----
__global__ __launch_bounds__(FBLK) void k_fill(const int* __restrict__ src, const int* __restrict__ dst,
                                               const float* __restrict__ w, int* __restrict__ bcur,
                                               unsigned long long* __restrict__ ep, int E, int nbuck) {
    __shared__ unsigned long long stg[FCHUNK];   // 64 KB
    __shared__ int sc[SCAN_N];                   // cnt exclusive scan -> lstart
    __shared__ int hist[NB_AL];
    __shared__ int gbase[NB_AL];
    const int t = threadIdx.x;
    for (int i = t; i < nbuck; i += FBLK) hist[i] = 0;
    __syncthreads();
    const int c0 = blockIdx.x * FCHUNK;
    const int c1 = min(c0 + FCHUNK, E);
    // pass 1: histogram; atomicAdd return value = unique in-(block,bucket) rank
    unsigned pk[FRPT];
#pragma unroll
    for (int k = 0; k < FRPT; ++k) {
        int e = c0 + t + k * FBLK;
        if (e < c1) {
            int d_ = dst[e];
            int b = d_ >> BSHIFT;
            int rank = atomicAdd(&hist[b], 1);            // rank < 8192 fits 13 bits
            pk[k] = ((unsigned)b << 20) | ((unsigned)(d_ & (BSIZE - 1)) << 13) | (unsigned)rank;
        }
    }
    __syncthreads();
    for (int i = t; i < SCAN_N; i += FBLK) sc[i] = (i < nbuck) ? hist[i] : 0;
    // Blelloch exclusive scan over SCAN_N
    for (int d = 1; d < SCAN_N; d <<= 1) {
        __syncthreads();
        int idx = (t + 1) * (d << 1) - 1;
        if (idx < SCAN_N) sc[idx] += sc[idx - d];
    }
    __syncthreads();
    if (t == 0) sc[SCAN_N - 1] = 0;
    for (int d = SCAN_N >> 1; d >= 1; d >>= 1) {
        __syncthreads();
        int idx = (t + 1) * (d << 1) - 1;
        if (idx < SCAN_N) { int tmp = sc[idx - d]; sc[idx - d] = sc[idx]; sc[idx] += tmp; }
    }
    __syncthreads();
    // reserve padded global runs (one 64B line per cursor -> low contention)
    for (int i = t; i < nbuck; i += FBLK) {
        int c = hist[i];
        int hp = (c + PADQ - 1) & ~(PADQ - 1);
        gbase[i] = hp ? atomicAdd(&bcur[i * BSTRIDE], hp) : 0;
    }
    __syncthreads();
    // scatter records into bucket-sorted LDS staging at sc[b]+rank (no atomics)
#pragma unroll
    for (int k = 0; k < FRPT; ++k) {
        int e = c0 + t + k * FBLK;
        if (e < c1) {
            unsigned p = pk[k];
            int b = p >> 20;
            unsigned dl = (p >> 13) & (BSIZE - 1);
            int rank = (int)(p & 8191u);
            stg[sc[b] + rank] = ((unsigned long long)f2h_bits(w[e]) << 32)
                              | (dl << 17) | (unsigned)src[e];
        }
    }
    __syncthreads();
    // flush: 16-lane groups copy whole padded bucket runs (coalesced full lines)
    const int grp = t >> 4, lgl = t & 15;            // 32 groups of 16 lanes
    for (int b = grp; b < nbuck; b += FBLK / 16) {
        int cb = hist[b];
        if (!cb) continue;
        int hp = (cb + PADQ - 1) & ~(PADQ - 1);
        int ls = sc[b];
        int gb = gbase[b];
        int lim = (b + 1) * CAPB;                    // capacity guard
        for (int o = lgl; o < hp; o += 16) {
            unsigned long long rec = (o < cb) ? stg[ls + o]
                : (((unsigned long long)(unsigned)(o & (BSIZE - 1))) << 17);   // hole: w=0
            int gi = gb + o;
            if (gi < lim) ep[gi] = rec;
        }
    }
}

// ---- stage B: register-staged in-bucket sort by dstloc; drops w=0 recs (holes);
// emits 4B recs (src<<15|w15) in place (upper half of own 8B region);
// deg/dis + per-node rs/re (in 4B-rec index units). base = b*CAPB fixed. ----
__global__ __launch_bounds__(SBLK) void k_sortB(unsigned long long* __restrict__ ep,
                                                const int* __restrict__ bcur, float* __restrict__ dis,
                                                int* __restrict__ rs, int* __restrict__ re, int n) {
    __shared__ unsigned stg[CAPB];     // 48 KB
    __shared__ int hist[BSIZE];
    __shared__ int excl[BSIZE + 1];
    __shared__ int cur[BSIZE];
    __shared__ float degl[BSIZE];
    const int b = blockIdx.x, t = threadIdx.x;
    if (t < BSIZE) { hist[t] = 0; degl[t] = 0.f; }
    __syncthreads();
    const int base = b * CAPB;
    const int cnt = min(bcur[b * BSTRIDE] - base, CAPB);
    unsigned long long r[RPT];
#pragma unroll
    for (int k = 0; k < RPT; ++k) {
        int e = t + k * SBLK;
        if (e < cnt) r[k] = ep[base + e];
    }
    // pass 1: histogram + weighted degree (skip w=0: holes)
#pragma unroll
    for (int k = 0; k < RPT; ++k) {
        int e = t + k * SBLK;
        if (e < cnt) {
            unsigned w16 = (unsigned)(r[k] >> 32);
            if (w16) {
                int dl = ((unsigned)r[k] >> 17) & (BSIZE - 1);
                atomicAdd(&hist[dl], 1);
                atomicAdd(&degl[dl], h2f_bits((unsigned short)w16));
            }
        }
    }
    __syncthreads();
    if (t == 0) {
        int run = 0;
        for (int k2 = 0; k2 < BSIZE; ++k2) { excl[k2] = run; run += hist[k2]; }
        excl[BSIZE] = run;
    }
    __syncthreads();
    if (t < BSIZE) {
        cur[t] = excl[t];
        int node = (b << BSHIFT) + t;
        if (node < n) {
            dis[node] = (float)(1.0 / sqrt((double)(degl[t] + 1.0f)));   // +1 self-loop
            rs[node] = 2 * base + excl[t];          // 4B-rec index units
            re[node] = 2 * base + excl[t] + hist[t];
        }
    }
    __syncthreads();
    // pass 2: compress + scatter into LDS at sorted position
#pragma unroll
    for (int k = 0; k < RPT; ++k) {
        int e = t + k * SBLK;
        if (e < cnt) {
            unsigned w16 = (unsigned)(r[k] >> 32);
            if (w16) {
                int dl = ((unsigned)r[k] >> 17) & (BSIZE - 1);
                int pos = atomicAdd(&cur[dl], 1);
                stg[pos] = (((unsigned)r[k] & NSRC_MASK) << 15) | (w16 & 0x7FFF);
            }
        }
    }
    __syncthreads();
    // write back coalesced into the upper-aliased 4B view of OWN region (race-free)
    unsigned* outp = (unsigned*)(ep + base);
    const int m = excl[BSIZE];
    for (int i = t; i < m; i += SBLK) outp[i] = stg[i];
}

// ---- dense: zs = fp16( dis * (act(xin) @ W) ) ; act = relu(x + bprev) if RELU ----
template<int FI, int FO, bool RELU>
__global__ __launch_bounds__(256) void k_dense(const float* __restrict__ xin, const float* __restrict__ W,
                                               const float* __restrict__ bprev, const float* __restrict__ dis,
                                               __half* __restrict__ zs, int n) {
    constexpr int NPB = 256 / FO;
    constexpr int XP = FI + 1;
    __shared__ float Wl[FI * FO];
    __shared__ float xs[NPB * XP];
    const int t = threadIdx.x;
    for (int i = t; i < FI * FO; i += 256) Wl[i] = W[i];
    const int node0 = blockIdx.x * NPB;
    for (int i = t; i < NPB * FI; i += 256) {
        int r = i / FI, c = i - r * FI;
        int node = node0 + r;
        float v = 0.f;
        if (node < n) {
            v = xin[node * FI + c];
            if constexpr (RELU) v = relu_(v + bprev[c]);
        }
        xs[r * XP + c] = v;
    }
    __syncthreads();
    const int r = t / FO, j = t - r * FO;
    const int node = node0 + r;
    if (node < n) {
        float s = 0.f;
#pragma unroll
        for (int k = 0; k < FI; ++k) s += xs[r * XP + k] * Wl[k * FO + j];
        zs[node * FO + j] = __float2half(s * dis[node]);
    }
}

// ---- aggregation FO=16 (R11): one wave per node, __half2 feature pairs.
// 8 feature lanes (j2: features 2*j2, 2*j2+1) x 8 edge groups (g), 4 chains/lane.
// acc[d] = dis[d] * ( zs[d] + sum_e w_e * zs[src_e] )   (rec = src<<15|w15) ----
__global__ __launch_bounds__(256) void k_agg16(const unsigned* __restrict__ epc, const int* __restrict__ rs,
                                               const int* __restrict__ re, const float* __restrict__ dis,
                                               const __half* __restrict__ zs, float* __restrict__ acc, int n) {
    const int wv = (blockIdx.x * 256 + threadIdx.x) >> 6;   // node
    if (wv >= n) return;
    const int lane = threadIdx.x & 63;
    const int j2 = lane & 7, g = lane >> 3;
    const __half2* __restrict__ zs2 = (const __half2*)zs;
    const int base = rs[wv], end = re[wv];
    float sx = 0.f, sy = 0.f;
    int e = base + g;
    for (; e + 24 < end; e += 32) {     // 4 independent rec->zs chains, 32 recs/wave-iter
        unsigned r0 = epc[e], r1 = epc[e + 8], r2 = epc[e + 16], r3 = epc[e + 24];
        __half2 z0 = zs2[(r0 >> 15) * 8 + j2];
        __half2 z1 = zs2[(r1 >> 15) * 8 + j2];
        __half2 z2 = zs2[(r2 >> 15) * 8 + j2];
        __half2 z3 = zs2[(r3 >> 15) * 8 + j2];
        float w0 = h2f_bits((unsigned short)(r0 & 0x7FFF));
        float w1 = h2f_bits((unsigned short)(r1 & 0x7FFF));
        float w2 = h2f_bits((unsigned short)(r2 & 0x7FFF));
        float w3 = h2f_bits((unsigned short)(r3 & 0x7FFF));
        float2 f0 = __half22float2(z0), f1 = __half22float2(z1);
        float2 f2 = __half22float2(z2), f3 = __half22float2(z3);
        sx += f0.x * w0 + f1.x * w1 + f2.x * w2 + f3.x * w3;
        sy += f0.y * w0 + f1.y * w1 + f2.y * w2 + f3.y * w3;
    }
    for (; e < end; e += 8) {
        unsigned r0 = epc[e];
        float w0 = h2f_bits((unsigned short)(r0 & 0x7FFF));
        float2 f0 = __half22float2(zs2[(r0 >> 15) * 8 + j2]);
        sx += f0.x * w0;
        sy += f0.y * w0;
    }
    sx += __shfl_xor(sx, 8, 64);  sy += __shfl_xor(sy, 8, 64);
    sx += __shfl_xor(sx, 16, 64); sy += __shfl_xor(sy, 16, 64);
    sx += __shfl_xor(sx, 32, 64); sy += __shfl_xor(sy, 32, 64);
    if (g == 0) {
        float2 zself = __half22float2(zs2[wv * 8 + j2]);
        float d = dis[wv];
        ((float2*)acc)[wv * 8 + j2] = make_float2(d * (zself.x + sx), d * (zself.y + sy));
    }
}

// ---- aggregation FO=1 + relu+bias, per-block partial sums ----
__global__ __launch_bounds__(256) void k_agg1(const unsigned* __restrict__ epc, const int* __restrict__ rs,
                                              const int* __restrict__ re, const float* __restrict__ dis,
                                              const __half* __restrict__ zs1, const float* __restrict__ b4,
                                              float* __restrict__ partial, int n) {
    const int t = threadIdx.x;
    const int wv = (blockIdx.x * 256 + t) >> 6;
    const int lane = t & 63;
    float v = 0.f;
    if (wv < n) {
        const int base = rs[wv], end = re[wv];
        float s = 0.f;
        for (int e = base + lane; e < end; e += 64) {
            unsigned r = epc[e];
            s += __half2float(zs1[r >> 15]) * h2f_bits((unsigned short)(r & 0x7FFF));
        }
#pragma unroll
        for (int o = 32; o > 0; o >>= 1) s += __shfl_xor(s, o, 64);
        if (lane == 0) v = relu_(dis[wv] * (__half2float(zs1[wv]) + s) + b4[0]);
    }
    __shared__ float wsum[4];
    if (lane == 0) wsum[t >> 6] = v;
    __syncthreads();
    if (t == 0) partial[blockIdx.x] = wsum[0] + wsum[1] + wsum[2] + wsum[3];
}

// ---- final: out[0] = sum(partial) / n ; one block ----
__global__ __launch_bounds__(1024) void k_final(const float* __restrict__ partial, float* __restrict__ out,
                                                int nb, int n) {
    const int t = threadIdx.x;
    float s = 0.f;
    for (int i = t; i < nb; i += 1024) s += partial[i];
#pragma unroll
    for (int o = 32; o > 0; o >>= 1) s += __shfl_xor(s, o, 64);
    __shared__ float wsum[16];
    if ((t & 63) == 0) wsum[t >> 6] = s;
    __syncthreads();
    if (t == 0) {
        float tot = 0.f;
#pragma unroll
        for (int k = 0; k < 16; ++k) tot += wsum[k];
        out[0] = tot / (float)n;
    }
}

static inline size_t align_up(size_t x) { return (x + 255) & ~(size_t)255; }

extern "C" void kernel_launch(void* const* d_in, const int* in_sizes, int n_in,
                              void* d_out, int out_size, void* d_ws, size_t ws_size,
                              hipStream_t stream) {
    const float* vf  = (const float*)d_in[0];   // [N,128]
    const int*   edg = (const int*)d_in[1];     // [2,E] int32
    const float* w   = (const float*)d_in[2];   // [E]
    const float* W1  = (const float*)d_in[3];
    const float* b1  = (const float*)d_in[4];
    const float* W2  = (const float*)d_in[5];
    const float* b2  = (const float*)d_in[6];
    const float* W3  = (const float*)d_in[7];
    const float* b3  = (const float*)d_in[8];
    const float* W4  = (const float*)d_in[9];
    const float* b4  = (const float*)d_in[10];
    float* out = (float*)d_out;

    const int n = in_sizes[0] / 128;   // 100000
    const int E = in_sizes[2];         // 6400000
    const int* src = edg;
    const int* dst = edg + E;
    const int nbuck = (n + BSIZE - 1) >> BSHIFT;   // 782
    const int gB = (E + FCHUNK - 1) / FCHUNK;      // 782

    char* ws = (char*)d_ws;
    size_t off = 0;
    int*                bcur    = (int*)(ws + off);                off += align_up((size_t)nbuck * BSTRIDE * 4);
    int*                rs      = (int*)(ws + off);                off += align_up((size_t)n * 4);
    int*                re      = (int*)(ws + off);                off += align_up((size_t)n * 4);
    float*              dis     = (float*)(ws + off);              off += align_up((size_t)n * 4);
    float*              partial = (float*)(ws + off);              off += align_up((size_t)((n + 3) / 4 + 1) * 4);
    unsigned long long* ep      = (unsigned long long*)(ws + off); off += align_up((size_t)nbuck * CAPB * 8);
    __half*             zsb     = (__half*)(ws + off);             off += align_up((size_t)n * 16 * 2);
    float*              acc     = (float*)(ws + off);              off += align_up((size_t)n * 16 * 4);
    __half*             zs1     = zsb;   // layer-4 dense output aliases zs (only n halves used)
    (void)ws_size;

    const int gD16 = (n + 15) / 16;                      // dense FO=16: 16 nodes/block
    const int gN = (n + 255) / 256;
    const int gW = (n + 3) / 4;                          // wave-per-node kernels
    const unsigned* epc = (const unsigned*)ep;           // 4B post-sort view

    k_zero<<<(nbuck + 255) / 256, 256, 0, stream>>>(bcur, nbuck);
    k_fill<<<gB, FBLK, 0, stream>>>(src, dst, w, bcur, ep, E, nbuck);
    k_sortB<<<nbuck, SBLK, 0, stream>>>(ep, bcur, dis, rs, re, n);

    // layer 1: 128 -> 16
    k_dense<128, 16, false><<<gD16, 256, 0, stream>>>(vf, W1, nullptr, dis, zsb, n);
    k_agg16<<<gW, 256, 0, stream>>>(epc, rs, re, dis, zsb, acc, n);
    // layer 2: 16 -> 16
    k_dense<16, 16, true><<<gD16, 256, 0, stream>>>(acc, W2, b1, dis, zsb, n);
    k_agg16<<<gW, 256, 0, stream>>>(epc, rs, re, dis, zsb, acc, n);
    // layer 3: 16 -> 16
    k_dense<16, 16, true><<<gD16, 256, 0, stream>>>(acc, W3, b2, dis, zsb, n);
    k_agg16<<<gW, 256, 0, stream>>>(epc, rs, re, dis, zsb, acc, n);
    // layer 4: 16 -> 1, then aggregation + relu+bias into per-block partials
    k_dense<16, 1, true><<<gN, 256, 0, stream>>>(acc, W4, b3, dis, zs1, n);
    k_agg1<<<gW, 256, 0, stream>>>(epc, rs, re, dis, zs1, b4, partial, n);
    k_final<<<1, 1024, 0, stream>>>(partial, out, gW, n);
}

// Round 5
// 532.610 us; speedup vs baseline: 1.0780x; 1.0103x over previous
//
#include <hip/hip_runtime.h>
#include <hip/hip_fp16.h>

// GCN critic: 4 layers (128->16->16->16->1), symmetric gcn_norm with self-loops,
// global mean pool. N=100000 nodes, E=6400000 edges.
// R14: single-wave shfl scans (k_fill: 20-barrier Blelloch -> 0-barrier wave scan,
// overlapped with global reservation on waves 1-7; k_sortB: serial t0 scan ->
// wave scan). Barriers/block in k_fill: ~26 -> 5.
// R13: line-padded cursors, rank-from-hist scatter. R12: fixed-capacity buckets,
// group-run flush. R11: k_agg16 __half2 feature pairs. Zero per-edge global atomics.

#define BSHIFT 7
#define BSIZE 128            // nodes per dst bucket
#define NB_AL 800            // >= nbuck = ceil(100000/128) = 782
#define SCAN_N 1024          // sc array size
#define CAPB 12288           // fixed slots per bucket (~12 sigma margin)
#define BSTRIDE 16           // ints per bucket cursor (one 64B line)
#define NSRC_MASK 131071     // 17-bit src (src < 131072)
#define FBLK 512
#define FCHUNK 8192          // edges per fill block
#define FRPT (FCHUNK / FBLK) // 16 edges per thread in fill
#define PADQ 8               // reservation quantum: 8 recs x 8B = one 64B line
#define SBLK 512
#define RPT (CAPB / SBLK)    // 24 records per thread in sortB
#define LPB 13               // buckets per lane in wave scan (13*64=832 >= 800)

static __device__ __forceinline__ float relu_(float v) { return v > 0.f ? v : 0.f; }

static __device__ __forceinline__ float h2f_bits(unsigned short b) {
    __half_raw hr; hr.x = b;
    return __half2float(__half(hr));
}
static __device__ __forceinline__ unsigned short f2h_bits(float f) {
    __half h = __float2half(f);
    __half_raw hr = *(__half_raw*)&h;
    return hr.x;
}

// ---- init bucket cursors to fixed bases (line-padded) ----
__global__ __launch_bounds__(256) void k_zero(int* __restrict__ bcur, int nbuck) {
    int i = blockIdx.x * 256 + threadIdx.x;
    if (i < nbuck) bcur[i * BSTRIDE] = i * CAPB;
}

// ---- fill: pass1 hist (atomicAdd return = in-bucket rank, kept in VGPRs) ->
// wave0: shfl-scan of hist (no barriers) || waves1-7: padded-run reservation ->
// rank-addressed LDS staging scatter -> 16-lane-group run flush.
// rec64 = fp16w<<32 | dstloc<<17 | src. Holes: w=0 records. ----
__global__ __launch_bounds__(FBLK) void k_fill(const int* __restrict__ src, const int* __restrict__ dst,
                                               const float* __restrict__ w, int* __restrict__ bcur,
                                               unsigned long long* __restrict__ ep, int E, int nbuck) {
    __shared__ unsigned long long stg[FCHUNK];   // 64 KB
    __shared__ int sc[SCAN_N];                   // exclusive scan of hist -> lstart
    __shared__ int hist[NB_AL];
    __shared__ int gbase[NB_AL];
    const int t = threadIdx.x;
    for (int i = t; i < nbuck; i += FBLK) hist[i] = 0;
    __syncthreads();
    const int c0 = blockIdx.x * FCHUNK;
    const int c1 = min(c0 + FCHUNK, E);
    // pass 1: histogram; atomicAdd return value = unique in-(block,bucket) rank
    unsigned pk[FRPT];
#pragma unroll
    for (int k = 0; k < FRPT; ++k) {
        int e = c0 + t + k * FBLK;
        if (e < c1) {
            int d_ = dst[e];
            int b = d_ >> BSHIFT;
            int rank = atomicAdd(&hist[b], 1);            // rank < 8192 fits 13 bits
            pk[k] = ((unsigned)b << 20) | ((unsigned)(d_ & (BSIZE - 1)) << 13) | (unsigned)rank;
        }
    }
    __syncthreads();
    // wave 0: exclusive scan of hist into sc (serial-in-lane + shfl wave scan).
    // waves 1-7 concurrently: reserve padded global runs (line-padded cursors).
    if (t < 64) {
        const int i0 = t * LPB;
        int v[LPB];
        int tot = 0;
#pragma unroll
        for (int k = 0; k < LPB; ++k) {
            int i = i0 + k;
            v[k] = (i < nbuck) ? hist[i] : 0;
        }
#pragma unroll
        for (int k = 0; k < LPB; ++k) { int x = v[k]; v[k] = tot; tot += x; }
        int inc = tot;
#pragma unroll
        for (int d = 1; d < 64; d <<= 1) {
            int y = __shfl_up(inc, d, 64);
            if (t >= d) inc += y;
        }
        const int excl = inc - tot;
#pragma unroll
        for (int k = 0; k < LPB; ++k) {
            int i = i0 + k;
            if (i < nbuck) sc[i] = excl + v[k];
        }
    } else {
        for (int i = t - 64; i < nbuck; i += FBLK - 64) {
            int c = hist[i];
            int hp = (c + PADQ - 1) & ~(PADQ - 1);
            gbase[i] = hp ? atomicAdd(&bcur[i * BSTRIDE], hp) : 0;
        }
    }
    __syncthreads();
    // scatter records into bucket-sorted LDS staging at sc[b]+rank (no atomics)
#pragma unroll
    for (int k = 0; k < FRPT; ++k) {
        int e = c0 + t + k * FBLK;
        if (e < c1) {
            unsigned p = pk[k];
            int b = p >> 20;
            unsigned dl = (p >> 13) & (BSIZE - 1);
            int rank = (int)(p & 8191u);
            stg[sc[b] + rank] = ((unsigned long long)f2h_bits(w[e]) << 32)
                              | (dl << 17) | (unsigned)src[e];
        }
    }
    __syncthreads();
    // flush: 16-lane groups copy whole padded bucket runs (coalesced full lines)
    const int grp = t >> 4, lgl = t & 15;            // 32 groups of 16 lanes
    for (int b = grp; b < nbuck; b += FBLK / 16) {
        int cb = hist[b];
        if (!cb) continue;
        int hp = (cb + PADQ - 1) & ~(PADQ - 1);
        int ls = sc[b];
        int gb = gbase[b];
        int lim = (b + 1) * CAPB;                    // capacity guard
        for (int o = lgl; o < hp; o += 16) {
            unsigned long long rec = (o < cb) ? stg[ls + o]
                : (((unsigned long long)(unsigned)(o & (BSIZE - 1))) << 17);   // hole: w=0
            int gi = gb + o;
            if (gi < lim) ep[gi] = rec;
        }
    }
}

// ---- stage B: register-staged in-bucket sort by dstloc; drops w=0 recs (holes);
// emits 4B recs (src<<15|w15) in place (upper half of own 8B region);
// deg/dis + per-node rs/re (in 4B-rec index units). base = b*CAPB fixed. ----
__global__ __launch_bounds__(SBLK) void k_sortB(unsigned long long* __restrict__ ep,
                                                const int* __restrict__ bcur, float* __restrict__ dis,
                                                int* __restrict__ rs, int* __restrict__ re, int n) {
    __shared__ unsigned stg[CAPB];     // 48 KB
    __shared__ int hist[BSIZE];
    __shared__ int excl[BSIZE + 1];
    __shared__ int cur[BSIZE];
    __shared__ float degl[BSIZE];
    const int b = blockIdx.x, t = threadIdx.x;
    if (t < BSIZE) { hist[t] = 0; degl[t] = 0.f; }
    __syncthreads();
    const int base = b * CAPB;
    const int cnt = min(bcur[b * BSTRIDE] - base, CAPB);
    unsigned long long r[RPT];
#pragma unroll
    for (int k = 0; k < RPT; ++k) {
        int e = t + k * SBLK;
        if (e < cnt) r[k] = ep[base + e];
    }
    // pass 1: histogram + weighted degree (skip w=0: holes)
#pragma unroll
    for (int k = 0; k < RPT; ++k) {
        int e = t + k * SBLK;
        if (e < cnt) {
            unsigned w16 = (unsigned)(r[k] >> 32);
            if (w16) {
                int dl = ((unsigned)r[k] >> 17) & (BSIZE - 1);
                atomicAdd(&hist[dl], 1);
                atomicAdd(&degl[dl], h2f_bits((unsigned short)w16));
            }
        }
    }
    __syncthreads();
    // wave 0: exclusive scan of hist[128] via shfl (2 values/lane)
    if (t < 64) {
        int a = hist[2 * t], c = hist[2 * t + 1];
        int tot = a + c;
        int inc = tot;
#pragma unroll
        for (int d = 1; d < 64; d <<= 1) {
            int y = __shfl_up(inc, d, 64);
            if (t >= d) inc += y;
        }
        int ex = inc - tot;
        excl[2 * t] = ex;
        excl[2 * t + 1] = ex + a;
        if (t == 63) excl[BSIZE] = inc;
    }
    __syncthreads();
    if (t < BSIZE) {
        cur[t] = excl[t];
        int node = (b << BSHIFT) + t;
        if (node < n) {
            dis[node] = (float)(1.0 / sqrt((double)(degl[t] + 1.0f)));   // +1 self-loop
            rs[node] = 2 * base + excl[t];          // 4B-rec index units
            re[node] = 2 * base + excl[t] + hist[t];
        }
    }
    __syncthreads();
    // pass 2: compress + scatter into LDS at sorted position
#pragma unroll
    for (int k = 0; k < RPT; ++k) {
        int e = t + k * SBLK;
        if (e < cnt) {
            unsigned w16 = (unsigned)(r[k] >> 32);
            if (w16) {
                int dl = ((unsigned)r[k] >> 17) & (BSIZE - 1);
                int pos = atomicAdd(&cur[dl], 1);
                stg[pos] = (((unsigned)r[k] & NSRC_MASK) << 15) | (w16 & 0x7FFF);
            }
        }
    }
    __syncthreads();
    // write back coalesced into the upper-aliased 4B view of OWN region (race-free)
    unsigned* outp = (unsigned*)(ep + base);
    const int m = excl[BSIZE];
    for (int i = t; i < m; i += SBLK) outp[i] = stg[i];
}

// ---- dense: zs = fp16( dis * (act(xin) @ W) ) ; act = relu(x + bprev) if RELU ----
template<int FI, int FO, bool RELU>
__global__ __launch_bounds__(256) void k_dense(const float* __restrict__ xin, const float* __restrict__ W,
                                               const float* __restrict__ bprev, const float* __restrict__ dis,
                                               __half* __restrict__ zs, int n) {
    constexpr int NPB = 256 / FO;
    constexpr int XP = FI + 1;
    __shared__ float Wl[FI * FO];
    __shared__ float xs[NPB * XP];
    const int t = threadIdx.x;
    for (int i = t; i < FI * FO; i += 256) Wl[i] = W[i];
    const int node0 = blockIdx.x * NPB;
    for (int i = t; i < NPB * FI; i += 256) {
        int r = i / FI, c = i - r * FI;
        int node = node0 + r;
        float v = 0.f;
        if (node < n) {
            v = xin[node * FI + c];
            if constexpr (RELU) v = relu_(v + bprev[c]);
        }
        xs[r * XP + c] = v;
    }
    __syncthreads();
    const int r = t / FO, j = t - r * FO;
    const int node = node0 + r;
    if (node < n) {
        float s = 0.f;
#pragma unroll
        for (int k = 0; k < FI; ++k) s += xs[r * XP + k] * Wl[k * FO + j];
        zs[node * FO + j] = __float2half(s * dis[node]);
    }
}

// ---- aggregation FO=16 (R11): one wave per node, __half2 feature pairs.
// 8 feature lanes (j2: features 2*j2, 2*j2+1) x 8 edge groups (g), 4 chains/lane.
// acc[d] = dis[d] * ( zs[d] + sum_e w_e * zs[src_e] )   (rec = src<<15|w15) ----
__global__ __launch_bounds__(256) void k_agg16(const unsigned* __restrict__ epc, const int* __restrict__ rs,
                                               const int* __restrict__ re, const float* __restrict__ dis,
                                               const __half* __restrict__ zs, float* __restrict__ acc, int n) {
    const int wv = (blockIdx.x * 256 + threadIdx.x) >> 6;   // node
    if (wv >= n) return;
    const int lane = threadIdx.x & 63;
    const int j2 = lane & 7, g = lane >> 3;
    const __half2* __restrict__ zs2 = (const __half2*)zs;
    const int base = rs[wv], end = re[wv];
    float sx = 0.f, sy = 0.f;
    int e = base + g;
    for (; e + 24 < end; e += 32) {     // 4 independent rec->zs chains, 32 recs/wave-iter
        unsigned r0 = epc[e], r1 = epc[e + 8], r2 = epc[e + 16], r3 = epc[e + 24];
        __half2 z0 = zs2[(r0 >> 15) * 8 + j2];
        __half2 z1 = zs2[(r1 >> 15) * 8 + j2];
        __half2 z2 = zs2[(r2 >> 15) * 8 + j2];
        __half2 z3 = zs2[(r3 >> 15) * 8 + j2];
        float w0 = h2f_bits((unsigned short)(r0 & 0x7FFF));
        float w1 = h2f_bits((unsigned short)(r1 & 0x7FFF));
        float w2 = h2f_bits((unsigned short)(r2 & 0x7FFF));
        float w3 = h2f_bits((unsigned short)(r3 & 0x7FFF));
        float2 f0 = __half22float2(z0), f1 = __half22float2(z1);
        float2 f2 = __half22float2(z2), f3 = __half22float2(z3);
        sx += f0.x * w0 + f1.x * w1 + f2.x * w2 + f3.x * w3;
        sy += f0.y * w0 + f1.y * w1 + f2.y * w2 + f3.y * w3;
    }
    for (; e < end; e += 8) {
        unsigned r0 = epc[e];
        float w0 = h2f_bits((unsigned short)(r0 & 0x7FFF));
        float2 f0 = __half22float2(zs2[(r0 >> 15) * 8 + j2]);
        sx += f0.x * w0;
        sy += f0.y * w0;
    }
    sx += __shfl_xor(sx, 8, 64);  sy += __shfl_xor(sy, 8, 64);
    sx += __shfl_xor(sx, 16, 64); sy += __shfl_xor(sy, 16, 64);
    sx += __shfl_xor(sx, 32, 64); sy += __shfl_xor(sy, 32, 64);
    if (g == 0) {
        float2 zself = __half22float2(zs2[wv * 8 + j2]);
        float d = dis[wv];
        ((float2*)acc)[wv * 8 + j2] = make_float2(d * (zself.x + sx), d * (zself.y + sy));
    }
}

// ---- aggregation FO=1 + relu+bias, per-block partial sums ----
__global__ __launch_bounds__(256) void k_agg1(const unsigned* __restrict__ epc, const int* __restrict__ rs,
                                              const int* __restrict__ re, const float* __restrict__ dis,
                                              const __half* __restrict__ zs1, const float* __restrict__ b4,
                                              float* __restrict__ partial, int n) {
    const int t = threadIdx.x;
    const int wv = (blockIdx.x * 256 + t) >> 6;
    const int lane = t & 63;
    float v = 0.f;
    if (wv < n) {
        const int base = rs[wv], end = re[wv];
        float s = 0.f;
        for (int e = base + lane; e < end; e += 64) {
            unsigned r = epc[e];
            s += __half2float(zs1[r >> 15]) * h2f_bits((unsigned short)(r & 0x7FFF));
        }
#pragma unroll
        for (int o = 32; o > 0; o >>= 1) s += __shfl_xor(s, o, 64);
        if (lane == 0) v = relu_(dis[wv] * (__half2float(zs1[wv]) + s) + b4[0]);
    }
    __shared__ float wsum[4];
    if (lane == 0) wsum[t >> 6] = v;
    __syncthreads();
    if (t == 0) partial[blockIdx.x] = wsum[0] + wsum[1] + wsum[2] + wsum[3];
}

// ---- final: out[0] = sum(partial) / n ; one block ----
__global__ __launch_bounds__(1024) void k_final(const float* __restrict__ partial, float* __restrict__ out,
                                                int nb, int n) {
    const int t = threadIdx.x;
    float s = 0.f;
    for (int i = t; i < nb; i += 1024) s += partial[i];
#pragma unroll
    for (int o = 32; o > 0; o >>= 1) s += __shfl_xor(s, o, 64);
    __shared__ float wsum[16];
    if ((t & 63) == 0) wsum[t >> 6] = s;
    __syncthreads();
    if (t == 0) {
        float tot = 0.f;
#pragma unroll
        for (int k = 0; k < 16; ++k) tot += wsum[k];
        out[0] = tot / (float)n;
    }
}

static inline size_t align_up(size_t x) { return (x + 255) & ~(size_t)255; }

extern "C" void kernel_launch(void* const* d_in, const int* in_sizes, int n_in,
                              void* d_out, int out_size, void* d_ws, size_t ws_size,
                              hipStream_t stream) {
    const float* vf  = (const float*)d_in[0];   // [N,128]
    const int*   edg = (const int*)d_in[1];     // [2,E] int32
    const float* w   = (const float*)d_in[2];   // [E]
    const float* W1  = (const float*)d_in[3];
    const float* b1  = (const float*)d_in[4];
    const float* W2  = (const float*)d_in[5];
    const float* b2  = (const float*)d_in[6];
    const float* W3  = (const float*)d_in[7];
    const float* b3  = (const float*)d_in[8];
    const float* W4  = (const float*)d_in[9];
    const float* b4  = (const float*)d_in[10];
    float* out = (float*)d_out;

    const int n = in_sizes[0] / 128;   // 100000
    const int E = in_sizes[2];         // 6400000
    const int* src = edg;
    const int* dst = edg + E;
    const int nbuck = (n + BSIZE - 1) >> BSHIFT;   // 782
    const int gB = (E + FCHUNK - 1) / FCHUNK;      // 782

    char* ws = (char*)d_ws;
    size_t off = 0;
    int*                bcur    = (int*)(ws + off);                off += align_up((size_t)nbuck * BSTRIDE * 4);
    int*                rs      = (int*)(ws + off);                off += align_up((size_t)n * 4);
    int*                re      = (int*)(ws + off);                off += align_up((size_t)n * 4);
    float*              dis     = (float*)(ws + off);              off += align_up((size_t)n * 4);
    float*              partial = (float*)(ws + off);              off += align_up((size_t)((n + 3) / 4 + 1) * 4);
    unsigned long long* ep      = (unsigned long long*)(ws + off); off += align_up((size_t)nbuck * CAPB * 8);
    __half*             zsb     = (__half*)(ws + off);             off += align_up((size_t)n * 16 * 2);
    float*              acc     = (float*)(ws + off);              off += align_up((size_t)n * 16 * 4);
    __half*             zs1     = zsb;   // layer-4 dense output aliases zs (only n halves used)
    (void)ws_size;

    const int gD16 = (n + 15) / 16;                      // dense FO=16: 16 nodes/block
    const int gN = (n + 255) / 256;
    const int gW = (n + 3) / 4;                          // wave-per-node kernels
    const unsigned* epc = (const unsigned*)ep;           // 4B post-sort view

    k_zero<<<(nbuck + 255) / 256, 256, 0, stream>>>(bcur, nbuck);
    k_fill<<<gB, FBLK, 0, stream>>>(src, dst, w, bcur, ep, E, nbuck);
    k_sortB<<<nbuck, SBLK, 0, stream>>>(ep, bcur, dis, rs, re, n);

    // layer 1: 128 -> 16
    k_dense<128, 16, false><<<gD16, 256, 0, stream>>>(vf, W1, nullptr, dis, zsb, n);
    k_agg16<<<gW, 256, 0, stream>>>(epc, rs, re, dis, zsb, acc, n);
    // layer 2: 16 -> 16
    k_dense<16, 16, true><<<gD16, 256, 0, stream>>>(acc, W2, b1, dis, zsb, n);
    k_agg16<<<gW, 256, 0, stream>>>(epc, rs, re, dis, zsb, acc, n);
    // layer 3: 16 -> 16
    k_dense<16, 16, true><<<gD16, 256, 0, stream>>>(acc, W3, b2, dis, zsb, n);
    k_agg16<<<gW, 256, 0, stream>>>(epc, rs, re, dis, zsb, acc, n);
    // layer 4: 16 -> 1, then aggregation + relu+bias into per-block partials
    k_dense<16, 1, true><<<gN, 256, 0, stream>>>(acc, W4, b3, dis, zs1, n);
    k_agg1<<<gW, 256, 0, stream>>>(epc, rs, re, dis, zs1, b4, partial, n);
    k_final<<<1, 1024, 0, stream>>>(partial, out, gW, n);
}

// Round 6
// 525.801 us; speedup vs baseline: 1.0920x; 1.0130x over previous
//
#include <hip/hip_runtime.h>
#include <hip/hip_fp16.h>

// GCN critic: 4 layers (128->16->16->16->1), symmetric gcn_norm with self-loops,
// global mean pool. N=100000 nodes, E=6400000 edges.
// R15: fill writes block-contiguous bucket-sorted runs (perfectly sequential,
// no global atomics, no padding/holes, no cursors) + per-block offset table scm;
// sortB gathers its bucket's 782 runs (L3-resident) into LDS, then sorts as
// before into a flat 4B-rec region epc4. k_zero deleted.
// R14: wave shfl scans. R11: k_agg16 __half2 feature pairs.

#define BSHIFT 7
#define BSIZE 128            // nodes per dst bucket
#define NB_AL 800            // >= nbuck+1 = 783
#define CAPL 8960            // recs per bucket cap (mean 8184 + 8.6 sigma)
#define MSTRIDE 784          // meta ints per fill-block row (>= nbuck+1, 64B-mult)
#define NSRC_MASK 131071     // 17-bit src
#define FBLK 512
#define FCHUNK 8192          // edges per fill block
#define FRPT (FCHUNK / FBLK) // 16
#define SBLK 512
#define RPT 18               // ceil(CAPL / SBLK)
#define LPB 13               // 13*64 = 832 >= 800 scan width

static __device__ __forceinline__ float relu_(float v) { return v > 0.f ? v : 0.f; }

static __device__ __forceinline__ float h2f_bits(unsigned short b) {
    __half_raw hr; hr.x = b;
    return __half2float(__half(hr));
}
static __device__ __forceinline__ unsigned short f2h_bits(float f) {
    __half h = __float2half(f);
    __half_raw hr = *(__half_raw*)&h;
    return hr.x;
}

// ---- fill: pass1 hist (atomicAdd return = in-(block,bucket) rank) ->
// wave0 shfl-scan (lstart, incl. total) -> rank-addressed LDS bucket-sorted
// staging -> LINEAR flush to block's own chunk [c0, c1) + meta row write.
// rec64 = fp16w<<32 | dstloc<<17 | src. No holes, no global atomics. ----
__global__ __launch_bounds__(FBLK) void k_fill(const int* __restrict__ src, const int* __restrict__ dst,
                                               const float* __restrict__ w,
                                               unsigned long long* __restrict__ ep,
                                               int* __restrict__ scm, int E, int nbuck) {
    __shared__ unsigned long long stg[FCHUNK];   // 64 KB
    __shared__ int sc[NB_AL];                    // exclusive scan of hist (lstart), sc[nbuck]=cnt
    __shared__ int hist[NB_AL];
    const int t = threadIdx.x;
    for (int i = t; i < nbuck; i += FBLK) hist[i] = 0;
    __syncthreads();
    const int c0 = blockIdx.x * FCHUNK;
    const int c1 = min(c0 + FCHUNK, E);
    // pass 1: histogram; atomicAdd return value = unique in-(block,bucket) rank
    unsigned pk[FRPT];
#pragma unroll
    for (int k = 0; k < FRPT; ++k) {
        int e = c0 + t + k * FBLK;
        if (e < c1) {
            int d_ = dst[e];
            int b = d_ >> BSHIFT;
            int rank = atomicAdd(&hist[b], 1);            // rank < 8192 fits 13 bits
            pk[k] = ((unsigned)b << 20) | ((unsigned)(d_ & (BSIZE - 1)) << 13) | (unsigned)rank;
        }
    }
    __syncthreads();
    // wave 0: exclusive scan of hist into sc[0..nbuck] (shfl wave scan, no barriers)
    if (t < 64) {
        const int i0 = t * LPB;
        int v[LPB];
        int tot = 0;
#pragma unroll
        for (int k = 0; k < LPB; ++k) {
            int i = i0 + k;
            v[k] = (i < nbuck) ? hist[i] : 0;
        }
#pragma unroll
        for (int k = 0; k < LPB; ++k) { int x = v[k]; v[k] = tot; tot += x; }
        int inc = tot;
#pragma unroll
        for (int d = 1; d < 64; d <<= 1) {
            int y = __shfl_up(inc, d, 64);
            if (t >= d) inc += y;
        }
        const int ex = inc - tot;
#pragma unroll
        for (int k = 0; k < LPB; ++k) {
            int i = i0 + k;
            if (i <= nbuck) sc[i] = ex + v[k];
        }
    }
    __syncthreads();
    // scatter records into bucket-sorted LDS staging at sc[b]+rank (no atomics)
#pragma unroll
    for (int k = 0; k < FRPT; ++k) {
        int e = c0 + t + k * FBLK;
        if (e < c1) {
            unsigned p = pk[k];
            int b = p >> 20;
            unsigned dl = (p >> 13) & (BSIZE - 1);
            int rank = (int)(p & 8191u);
            stg[sc[b] + rank] = ((unsigned long long)f2h_bits(w[e]) << 32)
                              | (dl << 17) | (unsigned)src[e];
        }
    }
    __syncthreads();
    // linear flush: block-contiguous, perfectly coalesced
    const int m = c1 - c0;
    for (int i = t; i < m; i += FBLK) ep[c0 + i] = stg[i];
    // meta row: run offsets for each bucket within this chunk
    int* row = scm + (size_t)blockIdx.x * MSTRIDE;
    for (int i = t; i <= nbuck; i += FBLK) row[i] = sc[i];
}

// ---- stage B: gather bucket b's runs from all fill-blocks into LDS, then
// register-staged in-bucket sort by dstloc; emits 4B recs (src<<15|w15) into
// flat epc region (base = b*CAPL); deg/dis + per-node rs/re (4B-rec units). ----
__global__ __launch_bounds__(SBLK) void k_sortB(const unsigned long long* __restrict__ ep,
                                                const int* __restrict__ scm,
                                                unsigned* __restrict__ epc, float* __restrict__ dis,
                                                int* __restrict__ rs, int* __restrict__ re,
                                                int n, int nbuck, int nblk) {
    __shared__ unsigned long long stg[CAPL];     // 70 KB (aliased as 4B after reg load)
    __shared__ int s_start[NB_AL];               // absolute run starts
    __shared__ unsigned short s_len[NB_AL];
    __shared__ unsigned short s_gex[NB_AL];      // exclusive scan of lens
    __shared__ int hist[BSIZE];
    __shared__ int excl[BSIZE + 1];
    __shared__ int cur[BSIZE];
    __shared__ float degl[BSIZE];
    __shared__ int s_m;
    const int b = blockIdx.x, t = threadIdx.x;
    // meta: run j = fill-block j's segment for bucket b
    for (int j = t; j < nblk; j += SBLK) {
        const int* row = scm + (size_t)j * MSTRIDE;
        int s0 = row[b], s1 = row[b + 1];
        s_start[j] = j * FCHUNK + s0;
        s_len[j] = (unsigned short)(s1 - s0);
    }
    if (t < BSIZE) { hist[t] = 0; degl[t] = 0.f; }
    __syncthreads();
    // wave 0: exclusive scan of lens -> s_gex, total -> s_m
    if (t < 64) {
        const int i0 = t * LPB;
        int v[LPB];
        int tot = 0;
#pragma unroll
        for (int k = 0; k < LPB; ++k) {
            int i = i0 + k;
            v[k] = (i < nblk) ? (int)s_len[i] : 0;
        }
#pragma unroll
        for (int k = 0; k < LPB; ++k) { int x = v[k]; v[k] = tot; tot += x; }
        int inc = tot;
#pragma unroll
        for (int d = 1; d < 64; d <<= 1) {
            int y = __shfl_up(inc, d, 64);
            if (t >= d) inc += y;
        }
        const int ex = inc - tot;
#pragma unroll
        for (int k = 0; k < LPB; ++k) {
            int i = i0 + k;
            if (i < nblk) s_gex[i] = (unsigned short)min(ex + v[k], CAPL);
        }
        if (t == 63) s_m = min(inc, CAPL);
    }
    __syncthreads();
    const int cnt = s_m;
    // gather runs into LDS (16-lane groups, one run at a time)
    const int grp = t >> 4, lgl = t & 15;        // 32 groups of 16 lanes
    for (int j = grp; j < nblk; j += SBLK / 16) {
        int len = s_len[j];
        if (!len) continue;
        int st = s_start[j];
        int gx = s_gex[j];
        for (int l = lgl; l < len; l += 16) {
            int pos = gx + l;
            if (pos < CAPL) stg[pos] = ep[st + l];
        }
    }
    __syncthreads();
    // load to registers, then LDS space is reusable as 4B staging
    unsigned long long r[RPT];
#pragma unroll
    for (int k = 0; k < RPT; ++k) {
        int e = t + k * SBLK;
        if (e < cnt) r[k] = stg[e];
    }
    __syncthreads();
    // pass 1: histogram + weighted degree (no holes exist)
#pragma unroll
    for (int k = 0; k < RPT; ++k) {
        int e = t + k * SBLK;
        if (e < cnt) {
            int dl = ((unsigned)r[k] >> 17) & (BSIZE - 1);
            atomicAdd(&hist[dl], 1);
            atomicAdd(&degl[dl], h2f_bits((unsigned short)(r[k] >> 32)));
        }
    }
    __syncthreads();
    // wave 0: exclusive scan of hist[128] via shfl (2 values/lane)
    if (t < 64) {
        int a = hist[2 * t], c = hist[2 * t + 1];
        int tot = a + c;
        int inc = tot;
#pragma unroll
        for (int d = 1; d < 64; d <<= 1) {
            int y = __shfl_up(inc, d, 64);
            if (t >= d) inc += y;
        }
        int ex = inc - tot;
        excl[2 * t] = ex;
        excl[2 * t + 1] = ex + a;
        if (t == 63) excl[BSIZE] = inc;
    }
    __syncthreads();
    const int base4 = b * CAPL;
    if (t < BSIZE) {
        cur[t] = excl[t];
        int node = (b << BSHIFT) + t;
        if (node < n) {
            dis[node] = (float)(1.0 / sqrt((double)(degl[t] + 1.0f)));   // +1 self-loop
            rs[node] = base4 + excl[t];          // 4B-rec index units
            re[node] = base4 + excl[t] + hist[t];
        }
    }
    __syncthreads();
    // pass 2: compress + scatter into aliased 4B LDS at sorted position
    unsigned* stg32 = (unsigned*)stg;
#pragma unroll
    for (int k = 0; k < RPT; ++k) {
        int e = t + k * SBLK;
        if (e < cnt) {
            int dl = ((unsigned)r[k] >> 17) & (BSIZE - 1);
            int pos = atomicAdd(&cur[dl], 1);
            stg32[pos] = (((unsigned)r[k] & NSRC_MASK) << 15) | ((unsigned)(r[k] >> 32) & 0x7FFF);
        }
    }
    __syncthreads();
    // write back coalesced into flat 4B region
    unsigned* outp = epc + base4;
    const int mm = excl[BSIZE];
    for (int i = t; i < mm; i += SBLK) outp[i] = stg32[i];
}

// ---- dense: zs = fp16( dis * (act(xin) @ W) ) ; act = relu(x + bprev) if RELU ----
template<int FI, int FO, bool RELU>
__global__ __launch_bounds__(256) void k_dense(const float* __restrict__ xin, const float* __restrict__ W,
                                               const float* __restrict__ bprev, const float* __restrict__ dis,
                                               __half* __restrict__ zs, int n) {
    constexpr int NPB = 256 / FO;
    constexpr int XP = FI + 1;
    __shared__ float Wl[FI * FO];
    __shared__ float xs[NPB * XP];
    const int t = threadIdx.x;
    for (int i = t; i < FI * FO; i += 256) Wl[i] = W[i];
    const int node0 = blockIdx.x * NPB;
    for (int i = t; i < NPB * FI; i += 256) {
        int r = i / FI, c = i - r * FI;
        int node = node0 + r;
        float v = 0.f;
        if (node < n) {
            v = xin[node * FI + c];
            if constexpr (RELU) v = relu_(v + bprev[c]);
        }
        xs[r * XP + c] = v;
    }
    __syncthreads();
    const int r = t / FO, j = t - r * FO;
    const int node = node0 + r;
    if (node < n) {
        float s = 0.f;
#pragma unroll
        for (int k = 0; k < FI; ++k) s += xs[r * XP + k] * Wl[k * FO + j];
        zs[node * FO + j] = __float2half(s * dis[node]);
    }
}

// ---- aggregation FO=16 (R11): one wave per node, __half2 feature pairs.
// acc[d] = dis[d] * ( zs[d] + sum_e w_e * zs[src_e] )   (rec = src<<15|w15) ----
__global__ __launch_bounds__(256) void k_agg16(const unsigned* __restrict__ epc, const int* __restrict__ rs,
                                               const int* __restrict__ re, const float* __restrict__ dis,
                                               const __half* __restrict__ zs, float* __restrict__ acc, int n) {
    const int wv = (blockIdx.x * 256 + threadIdx.x) >> 6;   // node
    if (wv >= n) return;
    const int lane = threadIdx.x & 63;
    const int j2 = lane & 7, g = lane >> 3;
    const __half2* __restrict__ zs2 = (const __half2*)zs;
    const int base = rs[wv], end = re[wv];
    float sx = 0.f, sy = 0.f;
    int e = base + g;
    for (; e + 24 < end; e += 32) {     // 4 independent rec->zs chains, 32 recs/wave-iter
        unsigned r0 = epc[e], r1 = epc[e + 8], r2 = epc[e + 16], r3 = epc[e + 24];
        __half2 z0 = zs2[(r0 >> 15) * 8 + j2];
        __half2 z1 = zs2[(r1 >> 15) * 8 + j2];
        __half2 z2 = zs2[(r2 >> 15) * 8 + j2];
        __half2 z3 = zs2[(r3 >> 15) * 8 + j2];
        float w0 = h2f_bits((unsigned short)(r0 & 0x7FFF));
        float w1 = h2f_bits((unsigned short)(r1 & 0x7FFF));
        float w2 = h2f_bits((unsigned short)(r2 & 0x7FFF));
        float w3 = h2f_bits((unsigned short)(r3 & 0x7FFF));
        float2 f0 = __half22float2(z0), f1 = __half22float2(z1);
        float2 f2 = __half22float2(z2), f3 = __half22float2(z3);
        sx += f0.x * w0 + f1.x * w1 + f2.x * w2 + f3.x * w3;
        sy += f0.y * w0 + f1.y * w1 + f2.y * w2 + f3.y * w3;
    }
    for (; e < end; e += 8) {
        unsigned r0 = epc[e];
        float w0 = h2f_bits((unsigned short)(r0 & 0x7FFF));
        float2 f0 = __half22float2(zs2[(r0 >> 15) * 8 + j2]);
        sx += f0.x * w0;
        sy += f0.y * w0;
    }
    sx += __shfl_xor(sx, 8, 64);  sy += __shfl_xor(sy, 8, 64);
    sx += __shfl_xor(sx, 16, 64); sy += __shfl_xor(sy, 16, 64);
    sx += __shfl_xor(sx, 32, 64); sy += __shfl_xor(sy, 32, 64);
    if (g == 0) {
        float2 zself = __half22float2(zs2[wv * 8 + j2]);
        float d = dis[wv];
        ((float2*)acc)[wv * 8 + j2] = make_float2(d * (zself.x + sx), d * (zself.y + sy));
    }
}

// ---- aggregation FO=1 + relu+bias, per-block partial sums ----
__global__ __launch_bounds__(256) void k_agg1(const unsigned* __restrict__ epc, const int* __restrict__ rs,
                                              const int* __restrict__ re, const float* __restrict__ dis,
                                              const __half* __restrict__ zs1, const float* __restrict__ b4,
                                              float* __restrict__ partial, int n) {
    const int t = threadIdx.x;
    const int wv = (blockIdx.x * 256 + t) >> 6;
    const int lane = t & 63;
    float v = 0.f;
    if (wv < n) {
        const int base = rs[wv], end = re[wv];
        float s = 0.f;
        for (int e = base + lane; e < end; e += 64) {
            unsigned r = epc[e];
            s += __half2float(zs1[r >> 15]) * h2f_bits((unsigned short)(r & 0x7FFF));
        }
#pragma unroll
        for (int o = 32; o > 0; o >>= 1) s += __shfl_xor(s, o, 64);
        if (lane == 0) v = relu_(dis[wv] * (__half2float(zs1[wv]) + s) + b4[0]);
    }
    __shared__ float wsum[4];
    if (lane == 0) wsum[t >> 6] = v;
    __syncthreads();
    if (t == 0) partial[blockIdx.x] = wsum[0] + wsum[1] + wsum[2] + wsum[3];
}

// ---- final: out[0] = sum(partial) / n ; one block ----
__global__ __launch_bounds__(1024) void k_final(const float* __restrict__ partial, float* __restrict__ out,
                                                int nb, int n) {
    const int t = threadIdx.x;
    float s = 0.f;
    for (int i = t; i < nb; i += 1024) s += partial[i];
#pragma unroll
    for (int o = 32; o > 0; o >>= 1) s += __shfl_xor(s, o, 64);
    __shared__ float wsum[16];
    if ((t & 63) == 0) wsum[t >> 6] = s;
    __syncthreads();
    if (t == 0) {
        float tot = 0.f;
#pragma unroll
        for (int k = 0; k < 16; ++k) tot += wsum[k];
        out[0] = tot / (float)n;
    }
}

static inline size_t align_up(size_t x) { return (x + 255) & ~(size_t)255; }

extern "C" void kernel_launch(void* const* d_in, const int* in_sizes, int n_in,
                              void* d_out, int out_size, void* d_ws, size_t ws_size,
                              hipStream_t stream) {
    const float* vf  = (const float*)d_in[0];   // [N,128]
    const int*   edg = (const int*)d_in[1];     // [2,E] int32
    const float* w   = (const float*)d_in[2];   // [E]
    const float* W1  = (const float*)d_in[3];
    const float* b1  = (const float*)d_in[4];
    const float* W2  = (const float*)d_in[5];
    const float* b2  = (const float*)d_in[6];
    const float* W3  = (const float*)d_in[7];
    const float* b3  = (const float*)d_in[8];
    const float* W4  = (const float*)d_in[9];
    const float* b4  = (const float*)d_in[10];
    float* out = (float*)d_out;

    const int n = in_sizes[0] / 128;   // 100000
    const int E = in_sizes[2];         // 6400000
    const int* src = edg;
    const int* dst = edg + E;
    const int nbuck = (n + BSIZE - 1) >> BSHIFT;   // 782
    const int gB = (E + FCHUNK - 1) / FCHUNK;      // 782 fill blocks

    char* ws = (char*)d_ws;
    size_t off = 0;
    int*                rs      = (int*)(ws + off);                off += align_up((size_t)n * 4);
    int*                re      = (int*)(ws + off);                off += align_up((size_t)n * 4);
    float*              dis     = (float*)(ws + off);              off += align_up((size_t)n * 4);
    float*              partial = (float*)(ws + off);              off += align_up((size_t)((n + 3) / 4 + 1) * 4);
    unsigned long long* ep      = (unsigned long long*)(ws + off); off += align_up((size_t)E * 8);
    int*                scm     = (int*)(ws + off);                off += align_up((size_t)gB * MSTRIDE * 4);
    unsigned*           epc     = (unsigned*)(ws + off);           off += align_up((size_t)nbuck * CAPL * 4);
    __half*             zsb     = (__half*)(ws + off);             off += align_up((size_t)n * 16 * 2);
    float*              acc     = (float*)(ws + off);              off += align_up((size_t)n * 16 * 4);
    __half*             zs1     = zsb;   // layer-4 dense output aliases zs (only n halves used)
    (void)ws_size;

    const int gD16 = (n + 15) / 16;                      // dense FO=16: 16 nodes/block
    const int gN = (n + 255) / 256;
    const int gW = (n + 3) / 4;                          // wave-per-node kernels

    k_fill<<<gB, FBLK, 0, stream>>>(src, dst, w, ep, scm, E, nbuck);
    k_sortB<<<nbuck, SBLK, 0, stream>>>(ep, scm, epc, dis, rs, re, n, nbuck, gB);

    // layer 1: 128 -> 16
    k_dense<128, 16, false><<<gD16, 256, 0, stream>>>(vf, W1, nullptr, dis, zsb, n);
    k_agg16<<<gW, 256, 0, stream>>>(epc, rs, re, dis, zsb, acc, n);
    // layer 2: 16 -> 16
    k_dense<16, 16, true><<<gD16, 256, 0, stream>>>(acc, W2, b1, dis, zsb, n);
    k_agg16<<<gW, 256, 0, stream>>>(epc, rs, re, dis, zsb, acc, n);
    // layer 3: 16 -> 16
    k_dense<16, 16, true><<<gD16, 256, 0, stream>>>(acc, W3, b2, dis, zsb, n);
    k_agg16<<<gW, 256, 0, stream>>>(epc, rs, re, dis, zsb, acc, n);
    // layer 4: 16 -> 1, then aggregation + relu+bias into per-block partials
    k_dense<16, 1, true><<<gN, 256, 0, stream>>>(acc, W4, b3, dis, zs1, n);
    k_agg1<<<gW, 256, 0, stream>>>(epc, rs, re, dis, zs1, b4, partial, n);
    k_final<<<1, 1024, 0, stream>>>(partial, out, gW, n);
}

// Round 7
// 511.239 us; speedup vs baseline: 1.1231x; 1.0285x over previous
//
#include <hip/hip_runtime.h>
#include <hip/hip_fp16.h>

// GCN critic: 4 layers (128->16->16->16->1), symmetric gcn_norm with self-loops,
// global mean pool. N=100000 nodes, E=6400000 edges.
// R16: sortB gather batches 4 runs/group-iteration (4x outstanding loads);
// agg16 software-pipelines rec prefetch one iteration ahead (breaks rec->zs
// serial chain). R15: block-contiguous fill + gather-side transpose.
// R14: wave shfl scans. R11: k_agg16 __half2 feature pairs.

#define BSHIFT 7
#define BSIZE 128            // nodes per dst bucket
#define NB_AL 800            // >= nbuck+1 = 783
#define CAPL 8960            // recs per bucket cap (mean 8184 + 8.6 sigma)
#define MSTRIDE 784          // meta ints per fill-block row (>= nbuck+1)
#define NSRC_MASK 131071     // 17-bit src
#define FBLK 512
#define FCHUNK 8192          // edges per fill block
#define FRPT (FCHUNK / FBLK) // 16
#define SBLK 512
#define RPT 18               // ceil(CAPL / SBLK)
#define LPB 13               // 13*64 = 832 >= 800 scan width

static __device__ __forceinline__ float relu_(float v) { return v > 0.f ? v : 0.f; }

static __device__ __forceinline__ float h2f_bits(unsigned short b) {
    __half_raw hr; hr.x = b;
    return __half2float(__half(hr));
}
static __device__ __forceinline__ unsigned short f2h_bits(float f) {
    __half h = __float2half(f);
    __half_raw hr = *(__half_raw*)&h;
    return hr.x;
}

// ---- fill: pass1 hist (atomicAdd return = in-(block,bucket) rank) ->
// wave0 shfl-scan (lstart, incl. total) -> rank-addressed LDS bucket-sorted
// staging -> LINEAR flush to block's own chunk [c0, c1) + meta row write.
// rec64 = fp16w<<32 | dstloc<<17 | src. No holes, no global atomics. ----
__global__ __launch_bounds__(FBLK) void k_fill(const int* __restrict__ src, const int* __restrict__ dst,
                                               const float* __restrict__ w,
                                               unsigned long long* __restrict__ ep,
                                               int* __restrict__ scm, int E, int nbuck) {
    __shared__ unsigned long long stg[FCHUNK];   // 64 KB
    __shared__ int sc[NB_AL];                    // exclusive scan of hist (lstart), sc[nbuck]=cnt
    __shared__ int hist[NB_AL];
    const int t = threadIdx.x;
    for (int i = t; i < nbuck; i += FBLK) hist[i] = 0;
    __syncthreads();
    const int c0 = blockIdx.x * FCHUNK;
    const int c1 = min(c0 + FCHUNK, E);
    // pass 1: histogram; atomicAdd return value = unique in-(block,bucket) rank
    unsigned pk[FRPT];
#pragma unroll
    for (int k = 0; k < FRPT; ++k) {
        int e = c0 + t + k * FBLK;
        if (e < c1) {
            int d_ = dst[e];
            int b = d_ >> BSHIFT;
            int rank = atomicAdd(&hist[b], 1);            // rank < 8192 fits 13 bits
            pk[k] = ((unsigned)b << 20) | ((unsigned)(d_ & (BSIZE - 1)) << 13) | (unsigned)rank;
        }
    }
    __syncthreads();
    // wave 0: exclusive scan of hist into sc[0..nbuck] (shfl wave scan, no barriers)
    if (t < 64) {
        const int i0 = t * LPB;
        int v[LPB];
        int tot = 0;
#pragma unroll
        for (int k = 0; k < LPB; ++k) {
            int i = i0 + k;
            v[k] = (i < nbuck) ? hist[i] : 0;
        }
#pragma unroll
        for (int k = 0; k < LPB; ++k) { int x = v[k]; v[k] = tot; tot += x; }
        int inc = tot;
#pragma unroll
        for (int d = 1; d < 64; d <<= 1) {
            int y = __shfl_up(inc, d, 64);
            if (t >= d) inc += y;
        }
        const int ex = inc - tot;
#pragma unroll
        for (int k = 0; k < LPB; ++k) {
            int i = i0 + k;
            if (i <= nbuck) sc[i] = ex + v[k];
        }
    }
    __syncthreads();
    // scatter records into bucket-sorted LDS staging at sc[b]+rank (no atomics)
#pragma unroll
    for (int k = 0; k < FRPT; ++k) {
        int e = c0 + t + k * FBLK;
        if (e < c1) {
            unsigned p = pk[k];
            int b = p >> 20;
            unsigned dl = (p >> 13) & (BSIZE - 1);
            int rank = (int)(p & 8191u);
            stg[sc[b] + rank] = ((unsigned long long)f2h_bits(w[e]) << 32)
                              | (dl << 17) | (unsigned)src[e];
        }
    }
    __syncthreads();
    // linear flush: block-contiguous, perfectly coalesced
    const int m = c1 - c0;
    for (int i = t; i < m; i += FBLK) ep[c0 + i] = stg[i];
    // meta row: run offsets for each bucket within this chunk
    int* row = scm + (size_t)blockIdx.x * MSTRIDE;
    for (int i = t; i <= nbuck; i += FBLK) row[i] = sc[i];
}

// ---- stage B: gather bucket b's runs (4 runs per 16-lane group iteration,
// 4x outstanding loads) into LDS, then register-staged in-bucket sort by
// dstloc; emits 4B recs (src<<15|w15) into flat epc region (base = b*CAPL);
// deg/dis + per-node rs/re (4B-rec units). ----
__global__ __launch_bounds__(SBLK) void k_sortB(const unsigned long long* __restrict__ ep,
                                                const int* __restrict__ scm,
                                                unsigned* __restrict__ epc, float* __restrict__ dis,
                                                int* __restrict__ rs, int* __restrict__ re,
                                                int n, int nbuck, int nblk) {
    __shared__ unsigned long long stg[CAPL];     // 70 KB (aliased as 4B after reg load)
    __shared__ int s_start[NB_AL];               // absolute run starts
    __shared__ unsigned short s_len[NB_AL];
    __shared__ unsigned short s_gex[NB_AL];      // exclusive scan of lens
    __shared__ int hist[BSIZE];
    __shared__ int excl[BSIZE + 1];
    __shared__ int cur[BSIZE];
    __shared__ float degl[BSIZE];
    __shared__ int s_m;
    const int b = blockIdx.x, t = threadIdx.x;
    // meta: run j = fill-block j's segment for bucket b
    for (int j = t; j < nblk; j += SBLK) {
        const int* row = scm + (size_t)j * MSTRIDE;
        int s0 = row[b], s1 = row[b + 1];
        s_start[j] = j * FCHUNK + s0;
        s_len[j] = (unsigned short)(s1 - s0);
    }
    if (t < BSIZE) { hist[t] = 0; degl[t] = 0.f; }
    __syncthreads();
    // wave 0: exclusive scan of lens -> s_gex, total -> s_m
    if (t < 64) {
        const int i0 = t * LPB;
        int v[LPB];
        int tot = 0;
#pragma unroll
        for (int k = 0; k < LPB; ++k) {
            int i = i0 + k;
            v[k] = (i < nblk) ? (int)s_len[i] : 0;
        }
#pragma unroll
        for (int k = 0; k < LPB; ++k) { int x = v[k]; v[k] = tot; tot += x; }
        int inc = tot;
#pragma unroll
        for (int d = 1; d < 64; d <<= 1) {
            int y = __shfl_up(inc, d, 64);
            if (t >= d) inc += y;
        }
        const int ex = inc - tot;
#pragma unroll
        for (int k = 0; k < LPB; ++k) {
            int i = i0 + k;
            if (i < nblk) s_gex[i] = (unsigned short)min(ex + v[k], CAPL);
        }
        if (t == 63) s_m = min(inc, CAPL);
    }
    __syncthreads();
    const int cnt = s_m;
    // gather runs into LDS: 16-lane groups, 4 runs per iteration (4 MLW)
    const int grp = t >> 4, lgl = t & 15;        // 32 groups of 16 lanes
    for (int j0 = grp * 4; j0 < nblk; j0 += 128) {
        int a0 = 0, a1 = 0, a2 = 0, a3 = 0;
        int l0 = 0, l1 = 0, l2 = 0, l3 = 0;
        int g0 = 0, g1 = 0, g2 = 0, g3 = 0;
        a0 = s_start[j0]; l0 = s_len[j0]; g0 = s_gex[j0];
        if (j0 + 1 < nblk) { a1 = s_start[j0 + 1]; l1 = s_len[j0 + 1]; g1 = s_gex[j0 + 1]; }
        if (j0 + 2 < nblk) { a2 = s_start[j0 + 2]; l2 = s_len[j0 + 2]; g2 = s_gex[j0 + 2]; }
        if (j0 + 3 < nblk) { a3 = s_start[j0 + 3]; l3 = s_len[j0 + 3]; g3 = s_gex[j0 + 3]; }
        unsigned long long v0 = 0, v1 = 0, v2 = 0, v3 = 0;
        if (lgl < l0) v0 = ep[a0 + lgl];
        if (lgl < l1) v1 = ep[a1 + lgl];
        if (lgl < l2) v2 = ep[a2 + lgl];
        if (lgl < l3) v3 = ep[a3 + lgl];
        if (lgl < l0) { int p = g0 + lgl; if (p < CAPL) stg[p] = v0; }
        if (lgl < l1) { int p = g1 + lgl; if (p < CAPL) stg[p] = v1; }
        if (lgl < l2) { int p = g2 + lgl; if (p < CAPL) stg[p] = v2; }
        if (lgl < l3) { int p = g3 + lgl; if (p < CAPL) stg[p] = v3; }
        // rare overflow (len > 16)
        for (int l = 16 + lgl; l < l0; l += 16) { int p = g0 + l; if (p < CAPL) stg[p] = ep[a0 + l]; }
        for (int l = 16 + lgl; l < l1; l += 16) { int p = g1 + l; if (p < CAPL) stg[p] = ep[a1 + l]; }
        for (int l = 16 + lgl; l < l2; l += 16) { int p = g2 + l; if (p < CAPL) stg[p] = ep[a2 + l]; }
        for (int l = 16 + lgl; l < l3; l += 16) { int p = g3 + l; if (p < CAPL) stg[p] = ep[a3 + l]; }
    }
    __syncthreads();
    // load to registers, then LDS space is reusable as 4B staging
    unsigned long long r[RPT];
#pragma unroll
    for (int k = 0; k < RPT; ++k) {
        int e = t + k * SBLK;
        if (e < cnt) r[k] = stg[e];
    }
    __syncthreads();
    // pass 1: histogram + weighted degree (no holes exist)
#pragma unroll
    for (int k = 0; k < RPT; ++k) {
        int e = t + k * SBLK;
        if (e < cnt) {
            int dl = ((unsigned)r[k] >> 17) & (BSIZE - 1);
            atomicAdd(&hist[dl], 1);
            atomicAdd(&degl[dl], h2f_bits((unsigned short)(r[k] >> 32)));
        }
    }
    __syncthreads();
    // wave 0: exclusive scan of hist[128] via shfl (2 values/lane)
    if (t < 64) {
        int a = hist[2 * t], c = hist[2 * t + 1];
        int tot = a + c;
        int inc = tot;
#pragma unroll
        for (int d = 1; d < 64; d <<= 1) {
            int y = __shfl_up(inc, d, 64);
            if (t >= d) inc += y;
        }
        int ex = inc - tot;
        excl[2 * t] = ex;
        excl[2 * t + 1] = ex + a;
        if (t == 63) excl[BSIZE] = inc;
    }
    __syncthreads();
    const int base4 = b * CAPL;
    if (t < BSIZE) {
        cur[t] = excl[t];
        int node = (b << BSHIFT) + t;
        if (node < n) {
            dis[node] = (float)(1.0 / sqrt((double)(degl[t] + 1.0f)));   // +1 self-loop
            rs[node] = base4 + excl[t];          // 4B-rec index units
            re[node] = base4 + excl[t] + hist[t];
        }
    }
    __syncthreads();
    // pass 2: compress + scatter into aliased 4B LDS at sorted position
    unsigned* stg32 = (unsigned*)stg;
#pragma unroll
    for (int k = 0; k < RPT; ++k) {
        int e = t + k * SBLK;
        if (e < cnt) {
            int dl = ((unsigned)r[k] >> 17) & (BSIZE - 1);
            int pos = atomicAdd(&cur[dl], 1);
            stg32[pos] = (((unsigned)r[k] & NSRC_MASK) << 15) | ((unsigned)(r[k] >> 32) & 0x7FFF);
        }
    }
    __syncthreads();
    // write back coalesced into flat 4B region
    unsigned* outp = epc + base4;
    const int mm = excl[BSIZE];
    for (int i = t; i < mm; i += SBLK) outp[i] = stg32[i];
}

// ---- dense: zs = fp16( dis * (act(xin) @ W) ) ; act = relu(x + bprev) if RELU ----
template<int FI, int FO, bool RELU>
__global__ __launch_bounds__(256) void k_dense(const float* __restrict__ xin, const float* __restrict__ W,
                                               const float* __restrict__ bprev, const float* __restrict__ dis,
                                               __half* __restrict__ zs, int n) {
    constexpr int NPB = 256 / FO;
    constexpr int XP = FI + 1;
    __shared__ float Wl[FI * FO];
    __shared__ float xs[NPB * XP];
    const int t = threadIdx.x;
    for (int i = t; i < FI * FO; i += 256) Wl[i] = W[i];
    const int node0 = blockIdx.x * NPB;
    for (int i = t; i < NPB * FI; i += 256) {
        int r = i / FI, c = i - r * FI;
        int node = node0 + r;
        float v = 0.f;
        if (node < n) {
            v = xin[node * FI + c];
            if constexpr (RELU) v = relu_(v + bprev[c]);
        }
        xs[r * XP + c] = v;
    }
    __syncthreads();
    const int r = t / FO, j = t - r * FO;
    const int node = node0 + r;
    if (node < n) {
        float s = 0.f;
#pragma unroll
        for (int k = 0; k < FI; ++k) s += xs[r * XP + k] * Wl[k * FO + j];
        zs[node * FO + j] = __float2half(s * dis[node]);
    }
}

// ---- aggregation FO=16 (R16): one wave per node, __half2 feature pairs,
// software-pipelined rec prefetch (next iter's 4 recs issued before current
// iter's zs gathers). acc[d] = dis[d]*(zs[d] + sum w_e*zs[src_e]). ----
__global__ __launch_bounds__(256) void k_agg16(const unsigned* __restrict__ epc, const int* __restrict__ rs,
                                               const int* __restrict__ re, const float* __restrict__ dis,
                                               const __half* __restrict__ zs, float* __restrict__ acc, int n) {
    const int wv = (blockIdx.x * 256 + threadIdx.x) >> 6;   // node
    if (wv >= n) return;
    const int lane = threadIdx.x & 63;
    const int j2 = lane & 7, g = lane >> 3;
    const __half2* __restrict__ zs2 = (const __half2*)zs;
    const int base = rs[wv], end = re[wv];
    float sx = 0.f, sy = 0.f;
    int e = base + g;
    unsigned ra0 = 0, ra1 = 0, ra2 = 0, ra3 = 0;
    if (e + 24 < end) { ra0 = epc[e]; ra1 = epc[e + 8]; ra2 = epc[e + 16]; ra3 = epc[e + 24]; }
    while (e + 24 < end) {
        const int en = e + 32;
        unsigned rb0 = 0, rb1 = 0, rb2 = 0, rb3 = 0;
        if (en + 24 < end) { rb0 = epc[en]; rb1 = epc[en + 8]; rb2 = epc[en + 16]; rb3 = epc[en + 24]; }
        __half2 z0 = zs2[(ra0 >> 15) * 8 + j2];
        __half2 z1 = zs2[(ra1 >> 15) * 8 + j2];
        __half2 z2 = zs2[(ra2 >> 15) * 8 + j2];
        __half2 z3 = zs2[(ra3 >> 15) * 8 + j2];
        float w0 = h2f_bits((unsigned short)(ra0 & 0x7FFF));
        float w1 = h2f_bits((unsigned short)(ra1 & 0x7FFF));
        float w2 = h2f_bits((unsigned short)(ra2 & 0x7FFF));
        float w3 = h2f_bits((unsigned short)(ra3 & 0x7FFF));
        float2 f0 = __half22float2(z0), f1 = __half22float2(z1);
        float2 f2 = __half22float2(z2), f3 = __half22float2(z3);
        sx += f0.x * w0 + f1.x * w1 + f2.x * w2 + f3.x * w3;
        sy += f0.y * w0 + f1.y * w1 + f2.y * w2 + f3.y * w3;
        ra0 = rb0; ra1 = rb1; ra2 = rb2; ra3 = rb3;
        e = en;
    }
    for (; e < end; e += 8) {
        unsigned r0 = epc[e];
        float w0 = h2f_bits((unsigned short)(r0 & 0x7FFF));
        float2 f0 = __half22float2(zs2[(r0 >> 15) * 8 + j2]);
        sx += f0.x * w0;
        sy += f0.y * w0;
    }
    sx += __shfl_xor(sx, 8, 64);  sy += __shfl_xor(sy, 8, 64);
    sx += __shfl_xor(sx, 16, 64); sy += __shfl_xor(sy, 16, 64);
    sx += __shfl_xor(sx, 32, 64); sy += __shfl_xor(sy, 32, 64);
    if (g == 0) {
        float2 zself = __half22float2(zs2[wv * 8 + j2]);
        float d = dis[wv];
        ((float2*)acc)[wv * 8 + j2] = make_float2(d * (zself.x + sx), d * (zself.y + sy));
    }
}

// ---- aggregation FO=1 + relu+bias, per-block partial sums ----
__global__ __launch_bounds__(256) void k_agg1(const unsigned* __restrict__ epc, const int* __restrict__ rs,
                                              const int* __restrict__ re, const float* __restrict__ dis,
                                              const __half* __restrict__ zs1, const float* __restrict__ b4,
                                              float* __restrict__ partial, int n) {
    const int t = threadIdx.x;
    const int wv = (blockIdx.x * 256 + t) >> 6;
    const int lane = t & 63;
    float v = 0.f;
    if (wv < n) {
        const int base = rs[wv], end = re[wv];
        float s = 0.f;
        for (int e = base + lane; e < end; e += 64) {
            unsigned r = epc[e];
            s += __half2float(zs1[r >> 15]) * h2f_bits((unsigned short)(r & 0x7FFF));
        }
#pragma unroll
        for (int o = 32; o > 0; o >>= 1) s += __shfl_xor(s, o, 64);
        if (lane == 0) v = relu_(dis[wv] * (__half2float(zs1[wv]) + s) + b4[0]);
    }
    __shared__ float wsum[4];
    if (lane == 0) wsum[t >> 6] = v;
    __syncthreads();
    if (t == 0) partial[blockIdx.x] = wsum[0] + wsum[1] + wsum[2] + wsum[3];
}

// ---- final: out[0] = sum(partial) / n ; one block ----
__global__ __launch_bounds__(1024) void k_final(const float* __restrict__ partial, float* __restrict__ out,
                                                int nb, int n) {
    const int t = threadIdx.x;
    float s = 0.f;
    for (int i = t; i < nb; i += 1024) s += partial[i];
#pragma unroll
    for (int o = 32; o > 0; o >>= 1) s += __shfl_xor(s, o, 64);
    __shared__ float wsum[16];
    if ((t & 63) == 0) wsum[t >> 6] = s;
    __syncthreads();
    if (t == 0) {
        float tot = 0.f;
#pragma unroll
        for (int k = 0; k < 16; ++k) tot += wsum[k];
        out[0] = tot / (float)n;
    }
}

static inline size_t align_up(size_t x) { return (x + 255) & ~(size_t)255; }

extern "C" void kernel_launch(void* const* d_in, const int* in_sizes, int n_in,
                              void* d_out, int out_size, void* d_ws, size_t ws_size,
                              hipStream_t stream) {
    const float* vf  = (const float*)d_in[0];   // [N,128]
    const int*   edg = (const int*)d_in[1];     // [2,E] int32
    const float* w   = (const float*)d_in[2];   // [E]
    const float* W1  = (const float*)d_in[3];
    const float* b1  = (const float*)d_in[4];
    const float* W2  = (const float*)d_in[5];
    const float* b2  = (const float*)d_in[6];
    const float* W3  = (const float*)d_in[7];
    const float* b3  = (const float*)d_in[8];
    const float* W4  = (const float*)d_in[9];
    const float* b4  = (const float*)d_in[10];
    float* out = (float*)d_out;

    const int n = in_sizes[0] / 128;   // 100000
    const int E = in_sizes[2];         // 6400000
    const int* src = edg;
    const int* dst = edg + E;
    const int nbuck = (n + BSIZE - 1) >> BSHIFT;   // 782
    const int gB = (E + FCHUNK - 1) / FCHUNK;      // 782 fill blocks

    char* ws = (char*)d_ws;
    size_t off = 0;
    int*                rs      = (int*)(ws + off);                off += align_up((size_t)n * 4);
    int*                re      = (int*)(ws + off);                off += align_up((size_t)n * 4);
    float*              dis     = (float*)(ws + off);              off += align_up((size_t)n * 4);
    float*              partial = (float*)(ws + off);              off += align_up((size_t)((n + 3) / 4 + 1) * 4);
    unsigned long long* ep      = (unsigned long long*)(ws + off); off += align_up((size_t)E * 8);
    int*                scm     = (int*)(ws + off);                off += align_up((size_t)gB * MSTRIDE * 4);
    unsigned*           epc     = (unsigned*)(ws + off);           off += align_up((size_t)nbuck * CAPL * 4);
    __half*             zsb     = (__half*)(ws + off);             off += align_up((size_t)n * 16 * 2);
    float*              acc     = (float*)(ws + off);              off += align_up((size_t)n * 16 * 4);
    __half*             zs1     = zsb;   // layer-4 dense output aliases zs (only n halves used)
    (void)ws_size;

    const int gD16 = (n + 15) / 16;                      // dense FO=16: 16 nodes/block
    const int gN = (n + 255) / 256;
    const int gW = (n + 3) / 4;                          // wave-per-node kernels

    k_fill<<<gB, FBLK, 0, stream>>>(src, dst, w, ep, scm, E, nbuck);
    k_sortB<<<nbuck, SBLK, 0, stream>>>(ep, scm, epc, dis, rs, re, n, nbuck, gB);

    // layer 1: 128 -> 16
    k_dense<128, 16, false><<<gD16, 256, 0, stream>>>(vf, W1, nullptr, dis, zsb, n);
    k_agg16<<<gW, 256, 0, stream>>>(epc, rs, re, dis, zsb, acc, n);
    // layer 2: 16 -> 16
    k_dense<16, 16, true><<<gD16, 256, 0, stream>>>(acc, W2, b1, dis, zsb, n);
    k_agg16<<<gW, 256, 0, stream>>>(epc, rs, re, dis, zsb, acc, n);
    // layer 3: 16 -> 16
    k_dense<16, 16, true><<<gD16, 256, 0, stream>>>(acc, W3, b2, dis, zsb, n);
    k_agg16<<<gW, 256, 0, stream>>>(epc, rs, re, dis, zsb, acc, n);
    // layer 4: 16 -> 1, then aggregation + relu+bias into per-block partials
    k_dense<16, 1, true><<<gN, 256, 0, stream>>>(acc, W4, b3, dis, zs1, n);
    k_agg1<<<gW, 256, 0, stream>>>(epc, rs, re, dis, zs1, b4, partial, n);
    k_final<<<1, 1024, 0, stream>>>(partial, out, gW, n);
}

// Round 10
// 469.025 us; speedup vs baseline: 1.2242x; 1.0900x over previous
//
#include <hip/hip_runtime.h>
#include <hip/hip_fp16.h>

// GCN critic: 4 layers (128->16->16->16->1), symmetric gcn_norm with self-loops,
// global mean pool. N=100000 nodes, E=6400000 edges.
// R17: k_agg16B = block-per-16-nodes with coalesced LDS rec staging (fixes the
// 32B-per-instruction epc streaming of wave-per-node agg); sortB stages 4B+1B
// (LDS 80->53 KB, 3 blocks/CU); dense uses float4 activation loads.
// R15/16: block-contiguous fill + batched gather transpose. R14: wave scans.

#define BSHIFT 7
#define BSIZE 128            // nodes per dst bucket
#define NB_AL 784            // >= nblk=782, >= nbuck+1=783
#define CAPL 8960            // recs per bucket cap (mean 8184 + 8.6 sigma)
#define MSTRIDE 784          // meta ints per fill-block row (>= nbuck+1)
#define NSRC_MASK 131071     // 17-bit src
#define FBLK 512
#define FCHUNK 8192          // edges per fill block
#define FRPT (FCHUNK / FBLK) // 16
#define SBLK 512
#define RPT 18               // ceil(CAPL / SBLK)
#define LPB 13               // 13*64 = 832 >= 784 scan width
#define ANODES 16            // nodes per agg block
#define ACAP 3072            // staged recs cap (mean ~1024)

static __device__ __forceinline__ float relu_(float v) { return v > 0.f ? v : 0.f; }

static __device__ __forceinline__ float h2f_bits(unsigned short b) {
    __half_raw hr; hr.x = b;
    return __half2float(__half(hr));
}
static __device__ __forceinline__ unsigned short f2h_bits(float f) {
    __half h = __float2half(f);
    __half_raw hr = *(__half_raw*)&h;
    return hr.x;
}

// ---- fill: pass1 hist (atomicAdd return = in-(block,bucket) rank) ->
// wave0 shfl-scan -> rank-addressed LDS bucket-sorted staging ->
// LINEAR flush to block's own chunk + meta row. rec64 = w16<<32|dl<<17|src ----
__global__ __launch_bounds__(FBLK) void k_fill(const int* __restrict__ src, const int* __restrict__ dst,
                                               const float* __restrict__ w,
                                               unsigned long long* __restrict__ ep,
                                               int* __restrict__ scm, int E, int nbuck) {
    __shared__ unsigned long long stg[FCHUNK];   // 64 KB
    __shared__ int sc[NB_AL];
    __shared__ int hist[NB_AL];
    const int t = threadIdx.x;
    for (int i = t; i < nbuck; i += FBLK) hist[i] = 0;
    __syncthreads();
    const int c0 = blockIdx.x * FCHUNK;
    const int c1 = min(c0 + FCHUNK, E);
    unsigned pk[FRPT];
#pragma unroll
    for (int k = 0; k < FRPT; ++k) {
        int e = c0 + t + k * FBLK;
        if (e < c1) {
            int d_ = dst[e];
            int b = d_ >> BSHIFT;
            int rank = atomicAdd(&hist[b], 1);
            pk[k] = ((unsigned)b << 20) | ((unsigned)(d_ & (BSIZE - 1)) << 13) | (unsigned)rank;
        }
    }
    __syncthreads();
    if (t < 64) {
        const int i0 = t * LPB;
        int v[LPB];
        int tot = 0;
#pragma unroll
        for (int k = 0; k < LPB; ++k) {
            int i = i0 + k;
            v[k] = (i < nbuck) ? hist[i] : 0;
        }
#pragma unroll
        for (int k = 0; k < LPB; ++k) { int x = v[k]; v[k] = tot; tot += x; }
        int inc = tot;
#pragma unroll
        for (int d = 1; d < 64; d <<= 1) {
            int y = __shfl_up(inc, d, 64);
            if (t >= d) inc += y;
        }
        const int ex = inc - tot;
#pragma unroll
        for (int k = 0; k < LPB; ++k) {
            int i = i0 + k;
            if (i <= nbuck) sc[i] = ex + v[k];
        }
    }
    __syncthreads();
#pragma unroll
    for (int k = 0; k < FRPT; ++k) {
        int e = c0 + t + k * FBLK;
        if (e < c1) {
            unsigned p = pk[k];
            int b = p >> 20;
            unsigned dl = (p >> 13) & (BSIZE - 1);
            int rank = (int)(p & 8191u);
            stg[sc[b] + rank] = ((unsigned long long)f2h_bits(w[e]) << 32)
                              | (dl << 17) | (unsigned)src[e];
        }
    }
    __syncthreads();
    const int m = c1 - c0;
    for (int i = t; i < m; i += FBLK) ep[c0 + i] = stg[i];
    int* row = scm + (size_t)blockIdx.x * MSTRIDE;
    for (int i = t; i <= nbuck; i += FBLK) row[i] = sc[i];
}

// ---- stage B: gather bucket b's runs (4 runs/group-iter) into COMPRESSED LDS
// (4B rec + 1B dstloc); register-stage; hist+deg; shfl scan; scatter sorted 4B
// recs; coalesced writeback to epc (base=b*CAPL). LDS ~53KB -> 3 blocks/CU. ----
__global__ __launch_bounds__(SBLK) void k_sortB(const unsigned long long* __restrict__ ep,
                                                const int* __restrict__ scm,
                                                unsigned* __restrict__ epc, float* __restrict__ dis,
                                                int* __restrict__ rs, int* __restrict__ re,
                                                int n, int nbuck, int nblk) {
    __shared__ unsigned stg4[CAPL];              // 35 KB (gather in, sorted out)
    __shared__ unsigned char dlb[CAPL];          // 8.75 KB
    __shared__ int s_start[NB_AL];
    __shared__ unsigned short s_len[NB_AL];
    __shared__ unsigned short s_gex[NB_AL];
    __shared__ int hist[BSIZE];
    __shared__ int excl[BSIZE + 1];
    __shared__ int cur[BSIZE];
    __shared__ float degl[BSIZE];
    __shared__ int s_m;
    const int b = blockIdx.x, t = threadIdx.x;
    for (int j = t; j < nblk; j += SBLK) {
        const int* row = scm + (size_t)j * MSTRIDE;
        int s0 = row[b], s1 = row[b + 1];
        s_start[j] = j * FCHUNK + s0;
        s_len[j] = (unsigned short)(s1 - s0);
    }
    if (t < BSIZE) { hist[t] = 0; degl[t] = 0.f; }
    __syncthreads();
    if (t < 64) {
        const int i0 = t * LPB;
        int v[LPB];
        int tot = 0;
#pragma unroll
        for (int k = 0; k < LPB; ++k) {
            int i = i0 + k;
            v[k] = (i < nblk) ? (int)s_len[i] : 0;
        }
#pragma unroll
        for (int k = 0; k < LPB; ++k) { int x = v[k]; v[k] = tot; tot += x; }
        int inc = tot;
#pragma unroll
        for (int d = 1; d < 64; d <<= 1) {
            int y = __shfl_up(inc, d, 64);
            if (t >= d) inc += y;
        }
        const int ex = inc - tot;
#pragma unroll
        for (int k = 0; k < LPB; ++k) {
            int i = i0 + k;
            if (i < nblk) s_gex[i] = (unsigned short)min(ex + v[k], CAPL);
        }
        if (t == 63) s_m = min(inc, CAPL);
    }
    __syncthreads();
    const int cnt = s_m;
    // gather: 16-lane groups, 4 runs per iteration; write compressed
    const int grp = t >> 4, lgl = t & 15;
    for (int j0 = grp * 4; j0 < nblk; j0 += 128) {
        int a0 = 0, a1 = 0, a2 = 0, a3 = 0;
        int l0 = 0, l1 = 0, l2 = 0, l3 = 0;
        int g0 = 0, g1 = 0, g2 = 0, g3 = 0;
        a0 = s_start[j0]; l0 = s_len[j0]; g0 = s_gex[j0];
        if (j0 + 1 < nblk) { a1 = s_start[j0 + 1]; l1 = s_len[j0 + 1]; g1 = s_gex[j0 + 1]; }
        if (j0 + 2 < nblk) { a2 = s_start[j0 + 2]; l2 = s_len[j0 + 2]; g2 = s_gex[j0 + 2]; }
        if (j0 + 3 < nblk) { a3 = s_start[j0 + 3]; l3 = s_len[j0 + 3]; g3 = s_gex[j0 + 3]; }
        unsigned long long v0 = 0, v1 = 0, v2 = 0, v3 = 0;
        if (lgl < l0) v0 = ep[a0 + lgl];
        if (lgl < l1) v1 = ep[a1 + lgl];
        if (lgl < l2) v2 = ep[a2 + lgl];
        if (lgl < l3) v3 = ep[a3 + lgl];
        if (lgl < l0) { int p = g0 + lgl; if (p < CAPL) { stg4[p] = (((unsigned)v0 & NSRC_MASK) << 15) | ((unsigned)(v0 >> 32) & 0x7FFF); dlb[p] = (unsigned char)(((unsigned)v0 >> 17) & (BSIZE - 1)); } }
        if (lgl < l1) { int p = g1 + lgl; if (p < CAPL) { stg4[p] = (((unsigned)v1 & NSRC_MASK) << 15) | ((unsigned)(v1 >> 32) & 0x7FFF); dlb[p] = (unsigned char)(((unsigned)v1 >> 17) & (BSIZE - 1)); } }
        if (lgl < l2) { int p = g2 + lgl; if (p < CAPL) { stg4[p] = (((unsigned)v2 & NSRC_MASK) << 15) | ((unsigned)(v2 >> 32) & 0x7FFF); dlb[p] = (unsigned char)(((unsigned)v2 >> 17) & (BSIZE - 1)); } }
        if (lgl < l3) { int p = g3 + lgl; if (p < CAPL) { stg4[p] = (((unsigned)v3 & NSRC_MASK) << 15) | ((unsigned)(v3 >> 32) & 0x7FFF); dlb[p] = (unsigned char)(((unsigned)v3 >> 17) & (BSIZE - 1)); } }
        for (int l = 16 + lgl; l < l0; l += 16) { int p = g0 + l; if (p < CAPL) { unsigned long long v = ep[a0 + l]; stg4[p] = (((unsigned)v & NSRC_MASK) << 15) | ((unsigned)(v >> 32) & 0x7FFF); dlb[p] = (unsigned char)(((unsigned)v >> 17) & (BSIZE - 1)); } }
        for (int l = 16 + lgl; l < l1; l += 16) { int p = g1 + l; if (p < CAPL) { unsigned long long v = ep[a1 + l]; stg4[p] = (((unsigned)v & NSRC_MASK) << 15) | ((unsigned)(v >> 32) & 0x7FFF); dlb[p] = (unsigned char)(((unsigned)v >> 17) & (BSIZE - 1)); } }
        for (int l = 16 + lgl; l < l2; l += 16) { int p = g2 + l; if (p < CAPL) { unsigned long long v = ep[a2 + l]; stg4[p] = (((unsigned)v & NSRC_MASK) << 15) | ((unsigned)(v >> 32) & 0x7FFF); dlb[p] = (unsigned char)(((unsigned)v >> 17) & (BSIZE - 1)); } }
        for (int l = 16 + lgl; l < l3; l += 16) { int p = g3 + l; if (p < CAPL) { unsigned long long v = ep[a3 + l]; stg4[p] = (((unsigned)v & NSRC_MASK) << 15) | ((unsigned)(v >> 32) & 0x7FFF); dlb[p] = (unsigned char)(((unsigned)v >> 17) & (BSIZE - 1)); } }
    }
    __syncthreads();
    // register-stage compressed recs
    unsigned r4[RPT];
    unsigned char dl8[RPT];
#pragma unroll
    for (int k = 0; k < RPT; ++k) {
        int e = t + k * SBLK;
        if (e < cnt) { r4[k] = stg4[e]; dl8[k] = dlb[e]; }
    }
    __syncthreads();
#pragma unroll
    for (int k = 0; k < RPT; ++k) {
        int e = t + k * SBLK;
        if (e < cnt) {
            int dl = dl8[k];
            atomicAdd(&hist[dl], 1);
            atomicAdd(&degl[dl], h2f_bits((unsigned short)(r4[k] & 0x7FFF)));
        }
    }
    __syncthreads();
    if (t < 64) {
        int a = hist[2 * t], c = hist[2 * t + 1];
        int tot = a + c;
        int inc = tot;
#pragma unroll
        for (int d = 1; d < 64; d <<= 1) {
            int y = __shfl_up(inc, d, 64);
            if (t >= d) inc += y;
        }
        int ex = inc - tot;
        excl[2 * t] = ex;
        excl[2 * t + 1] = ex + a;
        if (t == 63) excl[BSIZE] = inc;
    }
    __syncthreads();
    const int base4 = b * CAPL;
    if (t < BSIZE) {
        cur[t] = excl[t];
        int node = (b << BSHIFT) + t;
        if (node < n) {
            dis[node] = (float)(1.0 / sqrt((double)(degl[t] + 1.0f)));   // +1 self-loop
            rs[node] = base4 + excl[t];
            re[node] = base4 + excl[t] + hist[t];
        }
    }
    __syncthreads();
#pragma unroll
    for (int k = 0; k < RPT; ++k) {
        int e = t + k * SBLK;
        if (e < cnt) {
            int dl = dl8[k];
            int pos = atomicAdd(&cur[dl], 1);
            stg4[pos] = r4[k];
        }
    }
    __syncthreads();
    unsigned* outp = epc + base4;
    const int mm = excl[BSIZE];
    for (int i = t; i < mm; i += SBLK) outp[i] = stg4[i];
}

// ---- dense: zs = fp16( dis * (act(xin) @ W) ); float4 activation loads ----
template<int FI, int FO, bool RELU>
__global__ __launch_bounds__(256) void k_dense(const float* __restrict__ xin, const float* __restrict__ W,
                                               const float* __restrict__ bprev, const float* __restrict__ dis,
                                               __half* __restrict__ zs, int n) {
    constexpr int NPB = 256 / FO;
    constexpr int XP = FI + 4;                   // keeps float4 LDS stores 16B-aligned
    constexpr int F4 = FI / 4;
    __shared__ float Wl[FI * FO];
    __shared__ float xs[NPB * XP];
    const int t = threadIdx.x;
    for (int i = t; i < FI * FO; i += 256) Wl[i] = W[i];
    const int node0 = blockIdx.x * NPB;
    const float4* __restrict__ x4 = (const float4*)xin;
    for (int i = t; i < NPB * F4; i += 256) {
        int r = i / F4, c4 = i - r * F4;
        int node = node0 + r;
        float4 v = make_float4(0.f, 0.f, 0.f, 0.f);
        if (node < n) {
            v = x4[node * F4 + c4];
            if constexpr (RELU) {
                float4 bv = ((const float4*)bprev)[c4];
                v.x = relu_(v.x + bv.x); v.y = relu_(v.y + bv.y);
                v.z = relu_(v.z + bv.z); v.w = relu_(v.w + bv.w);
            }
        }
        *(float4*)&xs[r * XP + c4 * 4] = v;
    }
    __syncthreads();
    const int r = t / FO, j = t - r * FO;
    const int node = node0 + r;
    if (node < n) {
        float s = 0.f;
#pragma unroll
        for (int k = 0; k < FI; ++k) s += xs[r * XP + k] * Wl[k * FO + j];
        zs[node * FO + j] = __float2half(s * dis[node]);
    }
}

// ---- aggregation FO=16 (R17): block per 16 bucket-contiguous nodes.
// Stage the nodes' contiguous epc span into LDS (coalesced), then 4 waves x
// 4 nodes each aggregate from LDS recs + L2 zs gathers. ----
__global__ __launch_bounds__(256) void k_agg16B(const unsigned* __restrict__ epc, const int* __restrict__ rs,
                                                const int* __restrict__ re, const float* __restrict__ dis,
                                                const __half* __restrict__ zs, float* __restrict__ acc, int n) {
    __shared__ unsigned stg[ACAP];               // 12 KB
    const int bid = blockIdx.x;
    const int bucket = bid >> 3;
    const int node0 = (bucket << BSHIFT) + ((bid & 7) << 4);
    if (node0 >= n) return;
    const int t = threadIdx.x;
    const int last = min(node0 + ANODES - 1, n - 1);
    const int s0 = rs[node0];
    const int s1 = re[last];
    const int len = s1 - s0;
    const bool useLds = (len <= ACAP);
    if (useLds) {
        for (int i = t; i < len; i += 256) stg[i] = epc[s0 + i];
    }
    __syncthreads();
    const int wave = t >> 6, lane = t & 63;
    const int j2 = lane & 7, g = lane >> 3;
    const __half2* __restrict__ zs2 = (const __half2*)zs;
#pragma unroll
    for (int k = 0; k < 4; ++k) {
        const int node = node0 + (wave << 2) + k;
        if (node >= n) break;
        const int base = rs[node] - s0, endn = re[node] - s0;
        float sx = 0.f, sy = 0.f;
        int e = base + g;
        if (useLds) {
            for (; e + 24 < endn; e += 32) {
                unsigned r0 = stg[e], r1 = stg[e + 8], r2 = stg[e + 16], r3 = stg[e + 24];
                __half2 z0 = zs2[(r0 >> 15) * 8 + j2];
                __half2 z1 = zs2[(r1 >> 15) * 8 + j2];
                __half2 z2 = zs2[(r2 >> 15) * 8 + j2];
                __half2 z3 = zs2[(r3 >> 15) * 8 + j2];
                float w0 = h2f_bits((unsigned short)(r0 & 0x7FFF));
                float w1 = h2f_bits((unsigned short)(r1 & 0x7FFF));
                float w2 = h2f_bits((unsigned short)(r2 & 0x7FFF));
                float w3 = h2f_bits((unsigned short)(r3 & 0x7FFF));
                float2 f0 = __half22float2(z0), f1 = __half22float2(z1);
                float2 f2 = __half22float2(z2), f3 = __half22float2(z3);
                sx += f0.x * w0 + f1.x * w1 + f2.x * w2 + f3.x * w3;
                sy += f0.y * w0 + f1.y * w1 + f2.y * w2 + f3.y * w3;
            }
            for (; e < endn; e += 8) {
                unsigned r0 = stg[e];
                float w0 = h2f_bits((unsigned short)(r0 & 0x7FFF));
                float2 f0 = __half22float2(zs2[(r0 >> 15) * 8 + j2]);
                sx += f0.x * w0;
                sy += f0.y * w0;
            }
        } else {
            for (; e + 24 < endn; e += 32) {
                unsigned r0 = epc[s0 + e], r1 = epc[s0 + e + 8], r2 = epc[s0 + e + 16], r3 = epc[s0 + e + 24];
                __half2 z0 = zs2[(r0 >> 15) * 8 + j2];
                __half2 z1 = zs2[(r1 >> 15) * 8 + j2];
                __half2 z2 = zs2[(r2 >> 15) * 8 + j2];
                __half2 z3 = zs2[(r3 >> 15) * 8 + j2];
                float w0 = h2f_bits((unsigned short)(r0 & 0x7FFF));
                float w1 = h2f_bits((unsigned short)(r1 & 0x7FFF));
                float w2 = h2f_bits((unsigned short)(r2 & 0x7FFF));
                float w3 = h2f_bits((unsigned short)(r3 & 0x7FFF));
                float2 f0 = __half22float2(z0), f1 = __half22float2(z1);
                float2 f2 = __half22float2(z2), f3 = __half22float2(z3);
                sx += f0.x * w0 + f1.x * w1 + f2.x * w2 + f3.x * w3;
                sy += f0.y * w0 + f1.y * w1 + f2.y * w2 + f3.y * w3;
            }
            for (; e < endn; e += 8) {
                unsigned r0 = epc[s0 + e];
                float w0 = h2f_bits((unsigned short)(r0 & 0x7FFF));
                float2 f0 = __half22float2(zs2[(r0 >> 15) * 8 + j2]);
                sx += f0.x * w0;
                sy += f0.y * w0;
            }
        }
        sx += __shfl_xor(sx, 8, 64);  sy += __shfl_xor(sy, 8, 64);
        sx += __shfl_xor(sx, 16, 64); sy += __shfl_xor(sy, 16, 64);
        sx += __shfl_xor(sx, 32, 64); sy += __shfl_xor(sy, 32, 64);
        if (g == 0) {
            float2 zself = __half22float2(zs2[node * 8 + j2]);
            float d = dis[node];
            ((float2*)acc)[node * 8 + j2] = make_float2(d * (zself.x + sx), d * (zself.y + sy));
        }
    }
}

// ---- aggregation FO=1 + relu+bias, per-block partial sums ----
__global__ __launch_bounds__(256) void k_agg1(const unsigned* __restrict__ epc, const int* __restrict__ rs,
                                              const int* __restrict__ re, const float* __restrict__ dis,
                                              const __half* __restrict__ zs1, const float* __restrict__ b4,
                                              float* __restrict__ partial, int n) {
    const int t = threadIdx.x;
    const int wv = (blockIdx.x * 256 + t) >> 6;
    const int lane = t & 63;
    float v = 0.f;
    if (wv < n) {
        const int base = rs[wv], end = re[wv];
        float s = 0.f;
        for (int e = base + lane; e < end; e += 64) {
            unsigned r = epc[e];
            s += __half2float(zs1[r >> 15]) * h2f_bits((unsigned short)(r & 0x7FFF));
        }
#pragma unroll
        for (int o = 32; o > 0; o >>= 1) s += __shfl_xor(s, o, 64);
        if (lane == 0) v = relu_(dis[wv] * (__half2float(zs1[wv]) + s) + b4[0]);
    }
    __shared__ float wsum[4];
    if (lane == 0) wsum[t >> 6] = v;
    __syncthreads();
    if (t == 0) partial[blockIdx.x] = wsum[0] + wsum[1] + wsum[2] + wsum[3];
}

// ---- final: out[0] = sum(partial) / n ; one block ----
__global__ __launch_bounds__(1024) void k_final(const float* __restrict__ partial, float* __restrict__ out,
                                                int nb, int n) {
    const int t = threadIdx.x;
    float s = 0.f;
    for (int i = t; i < nb; i += 1024) s += partial[i];
#pragma unroll
    for (int o = 32; o > 0; o >>= 1) s += __shfl_xor(s, o, 64);
    __shared__ float wsum[16];
    if ((t & 63) == 0) wsum[t >> 6] = s;
    __syncthreads();
    if (t == 0) {
        float tot = 0.f;
#pragma unroll
        for (int k = 0; k < 16; ++k) tot += wsum[k];
        out[0] = tot / (float)n;
    }
}

static inline size_t align_up(size_t x) { return (x + 255) & ~(size_t)255; }

extern "C" void kernel_launch(void* const* d_in, const int* in_sizes, int n_in,
                              void* d_out, int out_size, void* d_ws, size_t ws_size,
                              hipStream_t stream) {
    const float* vf  = (const float*)d_in[0];   // [N,128]
    const int*   edg = (const int*)d_in[1];     // [2,E] int32
    const float* w   = (const float*)d_in[2];   // [E]
    const float* W1  = (const float*)d_in[3];
    const float* b1  = (const float*)d_in[4];
    const float* W2  = (const float*)d_in[5];
    const float* b2  = (const float*)d_in[6];
    const float* W3  = (const float*)d_in[7];
    const float* b3  = (const float*)d_in[8];
    const float* W4  = (const float*)d_in[9];
    const float* b4  = (const float*)d_in[10];
    float* out = (float*)d_out;

    const int n = in_sizes[0] / 128;   // 100000
    const int E = in_sizes[2];         // 6400000
    const int* src = edg;
    const int* dst = edg + E;
    const int nbuck = (n + BSIZE - 1) >> BSHIFT;   // 782
    const int gB = (E + FCHUNK - 1) / FCHUNK;      // 782 fill blocks

    char* ws = (char*)d_ws;
    size_t off = 0;
    int*                rs      = (int*)(ws + off);                off += align_up((size_t)n * 4);
    int*                re      = (int*)(ws + off);                off += align_up((size_t)n * 4);
    float*              dis     = (float*)(ws + off);              off += align_up((size_t)n * 4);
    float*              partial = (float*)(ws + off);              off += align_up((size_t)((n + 3) / 4 + 1) * 4);
    unsigned long long* ep      = (unsigned long long*)(ws + off); off += align_up((size_t)E * 8);
    int*                scm     = (int*)(ws + off);                off += align_up((size_t)gB * MSTRIDE * 4);
    unsigned*           epc     = (unsigned*)(ws + off);           off += align_up((size_t)nbuck * CAPL * 4);
    __half*             zsb     = (__half*)(ws + off);             off += align_up((size_t)n * 16 * 2);
    float*              acc     = (float*)(ws + off);              off += align_up((size_t)n * 16 * 4);
    __half*             zs1     = zsb;   // layer-4 dense output aliases zs (only n halves used)
    (void)ws_size;

    const int gD16 = (n + 15) / 16;                      // dense FO=16: 16 nodes/block
    const int gN = (n + 255) / 256;
    const int gW = (n + 3) / 4;                          // wave-per-node (agg1)
    const int gA = nbuck * 8;                            // agg16B: 16 nodes/block

    k_fill<<<gB, FBLK, 0, stream>>>(src, dst, w, ep, scm, E, nbuck);
    k_sortB<<<nbuck, SBLK, 0, stream>>>(ep, scm, epc, dis, rs, re, n, nbuck, gB);

    // layer 1: 128 -> 16
    k_dense<128, 16, false><<<gD16, 256, 0, stream>>>(vf, W1, nullptr, dis, zsb, n);
    k_agg16B<<<gA, 256, 0, stream>>>(epc, rs, re, dis, zsb, acc, n);
    // layer 2: 16 -> 16
    k_dense<16, 16, true><<<gD16, 256, 0, stream>>>(acc, W2, b1, dis, zsb, n);
    k_agg16B<<<gA, 256, 0, stream>>>(epc, rs, re, dis, zsb, acc, n);
    // layer 3: 16 -> 16
    k_dense<16, 16, true><<<gD16, 256, 0, stream>>>(acc, W3, b2, dis, zsb, n);
    k_agg16B<<<gA, 256, 0, stream>>>(epc, rs, re, dis, zsb, acc, n);
    // layer 4: 16 -> 1, then aggregation + relu+bias into per-block partials
    k_dense<16, 1, true><<<gN, 256, 0, stream>>>(acc, W4, b3, dis, zs1, n);
    k_agg1<<<gW, 256, 0, stream>>>(epc, rs, re, dis, zs1, b4, partial, n);
    k_final<<<1, 1024, 0, stream>>>(partial, out, gW, n);
}